// Round 7
// baseline (153.620 us; speedup 1.0000x reference)
//
#include <hip/hip_runtime.h>
#include <hip/hip_bf16.h>

#define BDIM 1024
#define LDIM 128
#define KDIM 16
#define DDIM 512
#define NLAB 131072
#define NNEG 2048
#define NPOS (BDIM * KDIM)      /* 16384 */
#define NSUB (NPOS + NNEG)      /* 18432 */
#define EPSV 0.1f
#define CV 2.1f
#define NBUCK 512               /* labels per bucket = 256 -> shift 8 */
#define QBLK (BDIM / 2)         /* 512 query blocks, 2 b each */
#define GT_BLOCKS (NBUCK * 8)   /* 512 buckets x 8 d-tiles = 4096 */

typedef __attribute__((ext_vector_type(8))) short s8v;
typedef __attribute__((ext_vector_type(4))) float f4v;
typedef __attribute__((ext_vector_type(4))) float fv4;
typedef __attribute__((ext_vector_type(4))) unsigned short us4;

static __device__ __forceinline__ unsigned short f2bf(float x) {
    union { float f; unsigned u; } v; v.f = x;
    unsigned r = v.u + 0x7FFF + ((v.u >> 16) & 1);   // RNE
    return (unsigned short)(r >> 16);
}
static __device__ __forceinline__ float bf2f(unsigned short h) {
    return __uint_as_float((unsigned)h << 16);
}

// ---------------- init: zero norms2/Zrow/accum/ticket ----------------
__global__ __launch_bounds__(256) void init_kernel(float* __restrict__ norms2,
                                                   float* __restrict__ Zrow,
                                                   float* __restrict__ accum,
                                                   int* __restrict__ ticket) {
    int j = blockIdx.x * 256 + threadIdx.x;   // grid covers NSUB
    if (j < NSUB) norms2[j] = 0.f;
    if (j < BDIM) Zrow[j] = 0.f;
    if (j < 2) accum[j] = 0.f;
    if (j == 0) *ticket = 0;
}

// ---------------- sortall: single-block bucket sort (count+scan+place) ----------------
__global__ __launch_bounds__(1024) void sortall_kernel(const int* __restrict__ labels,
                                                       const int* __restrict__ negs,
                                                       int* __restrict__ offs_end,
                                                       int* __restrict__ cntg,
                                                       int* __restrict__ srt_v,
                                                       int* __restrict__ rank) {
    __shared__ int sc[NBUCK];
    int t = threadIdx.x;
    if (t < NBUCK) sc[t] = 0;
    __syncthreads();
    int vs[NSUB / 1024];
    #pragma unroll
    for (int k = 0; k < NSUB / 1024; ++k) {
        int j = k * 1024 + t;
        int v = (j < NPOS) ? max(labels[j], 0) : negs[j - NPOS];
        vs[k] = v;
        atomicAdd(&sc[v >> 8], 1);
    }
    __syncthreads();
    int c = (t < NBUCK) ? sc[t] : 0;
    // inclusive scan over sc[0..511]
    for (int off = 1; off < NBUCK; off <<= 1) {
        int v2 = (t < NBUCK && t >= off) ? sc[t - off] : 0;
        __syncthreads();
        if (t < NBUCK) sc[t] += v2;
        __syncthreads();
    }
    if (t < NBUCK) { cntg[t] = c; sc[t] -= c; }   // sc = exclusive bucket base
    __syncthreads();
    #pragma unroll
    for (int k = 0; k < NSUB / 1024; ++k) {
        int j = k * 1024 + t;
        int v = vs[k];
        int r = atomicAdd(&sc[v >> 8], 1);
        srt_v[r] = v;
        rank[j] = r;
    }
    __syncthreads();
    if (t < NBUCK) offs_end[t] = sc[t];           // bucket end
}

// ---------------- main1: fused [query, 2 b/block] and [W bucket-stream] ----------------
__global__ __launch_bounds__(256) void main1_kernel(const float* __restrict__ Wk,
                                                    const int* __restrict__ srt_v,
                                                    const int* __restrict__ offs_end,
                                                    const int* __restrict__ cnt,
                                                    unsigned short* __restrict__ WT,
                                                    float* __restrict__ norms2,
                                                    const int* __restrict__ indices,
                                                    const float* __restrict__ mask,
                                                    const float* __restrict__ embed,
                                                    float* __restrict__ query,
                                                    unsigned short* __restrict__ qbf) {
    __shared__ __align__(16) unsigned short tile[256][65];   // 33 KB, aliased by query path
    int t = threadIdx.x;
    int w = t >> 6, l = t & 63;

    if (blockIdx.x < QBLK) {
        // ---- query: 2 b's per block; thread owns a float4 column slice ----
        int*   sidx  = (int*)&tile[0][0];     // [2][128]  bytes 0..1023
        float* smask = (float*)&tile[8][0];   // [2][128]  bytes 1040..2063
        float* red   = (float*)&tile[17][0];  // 4 floats
        float* snorm = (float*)&tile[18][0];  // 2 floats
        int half = t >> 7;                    // which b
        int tc = t & 127;                     // column slice
        int b = blockIdx.x * 2 + half;
        sidx[half * 128 + tc]  = indices[b * LDIM + tc];
        smask[half * 128 + tc] = mask[b * LDIM + tc];
        __syncthreads();
        float msum = 0.f;
        for (int i = 0; i < LDIM; ++i) msum += smask[half * 128 + i];
        fv4 acc = {0.f, 0.f, 0.f, 0.f};
        #pragma unroll 4
        for (int ll = 0; ll < LDIM; ++ll) {
            int   idx = sidx[half * 128 + ll];
            float m   = smask[half * 128 + ll];
            fv4 v = *(const fv4*)&embed[(size_t)idx * DDIM + tc * 4];
            acc += v * m;                     // embed rows cached normally (want L3)
        }
        float denom = fmaxf(msum, 1.0f);
        acc /= denom;
        float ss = acc[0] * acc[0] + acc[1] * acc[1] + acc[2] * acc[2] + acc[3] * acc[3];
        #pragma unroll
        for (int off = 32; off > 0; off >>= 1) ss += __shfl_xor(ss, off, 64);
        if (l == 0) red[w] = ss;
        __syncthreads();
        if (t == 0) {
            snorm[0] = sqrtf(red[0] + red[1]);
            snorm[1] = sqrtf(red[2] + red[3]);
        }
        __syncthreads();
        float inv = 1.f / fmaxf(snorm[half], 1e-4f);
        acc *= inv;
        __builtin_nontemporal_store(acc, (fv4*)&query[(size_t)b * DDIM + tc * 4]);
        us4 ob = { f2bf(acc[0]), f2bf(acc[1]), f2bf(acc[2]), f2bf(acc[3]) };
        __builtin_nontemporal_store(ob, (us4*)&qbf[(size_t)b * DDIM + tc * 4]);
    } else {
        // ---- W bucket-stream: block = (bucket g, 64-d tile) ----
        int bt = blockIdx.x - QBLK;
        int g  = bt >> 3;          // 0..511
        int dt = bt & 7;           // 0..7
        int d0 = dt * 64;
        #pragma unroll
        for (int i = 0; i < 16; ++i) {
            int dl = w * 16 + i;
            fv4 v = __builtin_nontemporal_load(
                (const fv4*)&Wk[(size_t)(d0 + dl) * NLAB + g * 256 + l * 4]);
            tile[l * 4 + 0][dl] = f2bf(v[0]);
            tile[l * 4 + 1][dl] = f2bf(v[1]);
            tile[l * 4 + 2][dl] = f2bf(v[2]);
            tile[l * 4 + 3][dl] = f2bf(v[3]);
        }
        __syncthreads();
        int rend = offs_end[g];
        int rbeg = rend - cnt[g];
        for (int r = rbeg + w; r < rend; r += 4) {
            int v = srt_v[r];
            int col = v - g * 256;
            unsigned short h = tile[col][l];
            __builtin_nontemporal_store(h, &WT[(size_t)r * DDIM + d0 + l]);
            float f = bf2f(h);
            float ss = f * f;
            ss += __shfl_xor(ss, 1, 64);  ss += __shfl_xor(ss, 2, 64);
            ss += __shfl_xor(ss, 4, 64);  ss += __shfl_xor(ss, 8, 64);
            ss += __shfl_xor(ss, 16, 64); ss += __shfl_xor(ss, 32, 64);
            if (l == 0) atomicAdd(&norms2[r], ss);
        }
    }
}

// ---------------- main2: fused [neg MFMA GEMM] and [pos dots] ----------------
static __device__ __forceinline__ float score_of(float acc, float nn) {
    float dot = acc / nn;
    dot = fminf(fmaxf(dot, -0.999f), 0.999f);
    return dot * dot / fmaxf(CV - 2.f * dot, EPSV);
}

__global__ __launch_bounds__(256) void main2_kernel(const unsigned short* __restrict__ qbf,
                                                    const float* __restrict__ query,
                                                    const unsigned short* __restrict__ WT,
                                                    const int* __restrict__ rank,
                                                    const float* __restrict__ norms2,
                                                    float* __restrict__ pos_scores,
                                                    float* __restrict__ Zrow) {
    int t = threadIdx.x;
    int w = t >> 6, l = t & 63;
    if (blockIdx.x < (BDIM / 64) * (NNEG / 64)) {
        // ---- negatives: 64x64 tile via MFMA ----
        __shared__ float rowsum[64];
        int bx = blockIdx.x;
        int mt = bx & 15, nt = bx >> 4;
        int wm = w >> 1, wn = w & 1;
        int lr = l & 15, lg = l >> 4;
        int m0 = mt * 64 + wm * 32;
        int n0 = nt * 64 + wn * 32;
        if (t < 64) rowsum[t] = 0.f;
        __syncthreads();

        int rB0 = rank[NPOS + n0 + lr];
        int rB1 = rank[NPOS + n0 + 16 + lr];
        const unsigned short* a0p = qbf + (size_t)(m0 + lr) * DDIM + lg * 8;
        const unsigned short* a1p = qbf + (size_t)(m0 + 16 + lr) * DDIM + lg * 8;
        const unsigned short* b0p = WT + (size_t)rB0 * DDIM + lg * 8;
        const unsigned short* b1p = WT + (size_t)rB1 * DDIM + lg * 8;

        f4v acc00 = {0.f, 0.f, 0.f, 0.f}, acc01 = acc00, acc10 = acc00, acc11 = acc00;
        #pragma unroll
        for (int k0 = 0; k0 < DDIM; k0 += 32) {
            s8v a0 = *(const s8v*)(a0p + k0);
            s8v a1 = *(const s8v*)(a1p + k0);
            s8v b0 = *(const s8v*)(b0p + k0);
            s8v b1 = *(const s8v*)(b1p + k0);
            acc00 = __builtin_amdgcn_mfma_f32_16x16x32_bf16(a0, b0, acc00, 0, 0, 0);
            acc01 = __builtin_amdgcn_mfma_f32_16x16x32_bf16(a0, b1, acc01, 0, 0, 0);
            acc10 = __builtin_amdgcn_mfma_f32_16x16x32_bf16(a1, b0, acc10, 0, 0, 0);
            acc11 = __builtin_amdgcn_mfma_f32_16x16x32_bf16(a1, b1, acc11, 0, 0, 0);
        }

        float nn0 = fmaxf(sqrtf(norms2[rB0]), 1e-4f);
        float nn1 = fmaxf(sqrtf(norms2[rB1]), 1e-4f);
        float s[8];
        #pragma unroll
        for (int i = 0; i < 4; ++i) {
            s[i]     = score_of(acc00[i], nn0) + score_of(acc01[i], nn1);
            s[4 + i] = score_of(acc10[i], nn0) + score_of(acc11[i], nn1);
        }
        #pragma unroll
        for (int i = 0; i < 8; ++i) {
            s[i] += __shfl_xor(s[i], 1, 64);
            s[i] += __shfl_xor(s[i], 2, 64);
            s[i] += __shfl_xor(s[i], 4, 64);
            s[i] += __shfl_xor(s[i], 8, 64);
        }
        if (lr == 0) {
            #pragma unroll
            for (int i = 0; i < 4; ++i) {
                atomicAdd(&rowsum[wm * 32 + lg * 4 + i], s[i]);
                atomicAdd(&rowsum[wm * 32 + 16 + lg * 4 + i], s[4 + i]);
            }
        }
        __syncthreads();
        if (t < 64) atomicAdd(&Zrow[mt * 64 + t], rowsum[t]);
    } else {
        // ---- positives: wave handles one b (16 j) ----
        int px = blockIdx.x - (BDIM / 64) * (NNEG / 64);
        int b = px * 4 + w;
        int j = b * KDIM + (l & 15);
        int r = rank[j];
        int g = l >> 4;
        const unsigned short* wrow = WT + (size_t)r * DDIM + g * 128;
        const float* qrow = query + (size_t)b * DDIM + g * 128;
        float acc = 0.f;
        #pragma unroll
        for (int kk = 0; kk < 128; kk += 8) {
            ushort4 w0 = *(const ushort4*)&wrow[kk];
            ushort4 w1 = *(const ushort4*)&wrow[kk + 4];
            float4 q0 = *(const float4*)&qrow[kk];
            float4 q1 = *(const float4*)&qrow[kk + 4];
            acc += bf2f(w0.x) * q0.x + bf2f(w0.y) * q0.y + bf2f(w0.z) * q0.z + bf2f(w0.w) * q0.w
                 + bf2f(w1.x) * q1.x + bf2f(w1.y) * q1.y + bf2f(w1.z) * q1.z + bf2f(w1.w) * q1.w;
        }
        acc += __shfl_xor(acc, 16, 64);
        acc += __shfl_xor(acc, 32, 64);
        if (l < 16) {
            float nrm = fmaxf(sqrtf(norms2[r]), 1e-4f);
            float dot = fminf(fmaxf(acc / nrm, -0.999f), 0.999f);
            float sc = dot * dot / fmaxf(CV - 2.f * dot, EPSV);
            pos_scores[j] = sc;
            float s = sc;
            s += __shfl_xor(s, 1, 64); s += __shfl_xor(s, 2, 64);
            s += __shfl_xor(s, 4, 64); s += __shfl_xor(s, 8, 64);
            if (l == 0) atomicAdd(&Zrow[b], s);
        }
    }
}

// ---------------- finalize (+writeout via ticket) ----------------
__global__ __launch_bounds__(256) void finalize_kernel(const float* __restrict__ pos_scores,
                                                       const float* __restrict__ label_mask,
                                                       const float* __restrict__ Zrow,
                                                       float* __restrict__ accum,
                                                       int* __restrict__ ticket,
                                                       float* __restrict__ out) {
    int j = blockIdx.x * 256 + threadIdx.x;
    int b = j >> 4;
    float lm = label_mask[j];
    float logZ = logf(Zrow[b] + (float)(KDIM + NNEG) * 1e-8f);
    float v = lm * (logf(pos_scores[j] + 1e-8f) - logZ);
    #pragma unroll
    for (int off = 32; off > 0; off >>= 1) {
        v  += __shfl_down(v, off, 64);
        lm += __shfl_down(lm, off, 64);
    }
    __shared__ float rv[4], rl[4];
    int wid = threadIdx.x >> 6, lane = threadIdx.x & 63;
    if (lane == 0) { rv[wid] = v; rl[wid] = lm; }
    __syncthreads();
    if (threadIdx.x == 0) {
        atomicAdd(&accum[0], rv[0] + rv[1] + rv[2] + rv[3]);
        atomicAdd(&accum[1], rl[0] + rl[1] + rl[2] + rl[3]);
        __threadfence();
        int old = atomicAdd(ticket, 1);
        if (old == (int)gridDim.x - 1) {
            float a = atomicAdd(&accum[0], 0.f);
            float m = atomicAdd(&accum[1], 0.f);
            out[0] = -a / (m + 1e-6f);
        }
    }
}

extern "C" void kernel_launch(void* const* d_in, const int* in_sizes, int n_in,
                              void* d_out, int out_size, void* d_ws, size_t ws_size,
                              hipStream_t stream) {
    const int*   indices    = (const int*)  d_in[0];
    const float* mask       = (const float*)d_in[1];
    const int*   labels     = (const int*)  d_in[2];
    const float* label_mask = (const float*)d_in[3];
    const int*   negs       = (const int*)  d_in[4];
    const float* embed      = (const float*)d_in[5];
    const float* Wk         = (const float*)d_in[6];
    float* out = (float*)d_out;

    // workspace layout (~25 MB)
    unsigned short* WT  = (unsigned short*)d_ws;                    // NSUB*DDIM bf16
    float* query      = (float*)(WT + (size_t)NSUB * DDIM);         // BDIM*DDIM f32
    unsigned short* qbf = (unsigned short*)(query + (size_t)BDIM * DDIM); // BDIM*DDIM bf16
    int*   srt_v      = (int*)(qbf + (size_t)BDIM * DDIM);          // NSUB
    int*   rank       = srt_v + NSUB;                               // NSUB
    float* norms2     = (float*)(rank + NSUB);                      // NSUB
    float* pos_scores = norms2 + NSUB;                              // NPOS
    float* Zrow       = pos_scores + NPOS;                          // BDIM
    float* accum      = Zrow + BDIM;                                // 2
    int*   ticket     = (int*)(accum + 2);                          // 1
    int*   cntg       = ticket + 1;                                 // NBUCK
    int*   offs_end   = cntg + NBUCK;                               // NBUCK

    init_kernel<<<NSUB / 256, 256, 0, stream>>>(norms2, Zrow, accum, ticket);
    sortall_kernel<<<1, 1024, 0, stream>>>(labels, negs, offs_end, cntg, srt_v, rank);
    main1_kernel<<<QBLK + GT_BLOCKS, 256, 0, stream>>>(Wk, srt_v, offs_end, cntg, WT, norms2,
                                                       indices, mask, embed, query, qbf);
    main2_kernel<<<(BDIM / 64) * (NNEG / 64) + NPOS / 64, 256, 0, stream>>>(
        qbf, query, WT, rank, norms2, pos_scores, Zrow);
    finalize_kernel<<<NPOS / 256, 256, 0, stream>>>(pos_scores, label_mask, Zrow,
                                                    accum, ticket, out);
}

// Round 8
// 152.039 us; speedup vs baseline: 1.0104x; 1.0104x over previous
//
#include <hip/hip_runtime.h>
#include <hip/hip_bf16.h>

#define BDIM 1024
#define LDIM 128
#define KDIM 16
#define DDIM 512
#define NLAB 131072
#define NNEG 2048
#define NPOS (BDIM * KDIM)      /* 16384 */
#define NSUB (NPOS + NNEG)      /* 18432 */
#define EPSV 0.1f
#define CV 2.1f
#define NBUCK 512               /* labels per bucket = 256 -> shift 8 */
#define GT_BLOCKS (NBUCK * 8)   /* 512 buckets x 8 d-tiles = 4096 */

typedef __attribute__((ext_vector_type(8))) short s8v;
typedef __attribute__((ext_vector_type(4))) float f4v;
typedef __attribute__((ext_vector_type(4))) float fv4;

static __device__ __forceinline__ unsigned short f2bf(float x) {
    union { float f; unsigned u; } v; v.f = x;
    unsigned r = v.u + 0x7FFF + ((v.u >> 16) & 1);   // RNE
    return (unsigned short)(r >> 16);
}
static __device__ __forceinline__ float bf2f(unsigned short h) {
    return __uint_as_float((unsigned)h << 16);
}

// ---------------- init: zero norms2/Zrow/accum/ticket ----------------
__global__ __launch_bounds__(256) void init_kernel(float* __restrict__ norms2,
                                                   float* __restrict__ Zrow,
                                                   float* __restrict__ accum,
                                                   int* __restrict__ ticket) {
    int j = blockIdx.x * 256 + threadIdx.x;   // grid covers NSUB
    if (j < NSUB) norms2[j] = 0.f;
    if (j < BDIM) Zrow[j] = 0.f;
    if (j < 2) accum[j] = 0.f;
    if (j == 0) *ticket = 0;
}

// ---------------- sortall: single-block bucket sort (count+scan+place) ----------------
__global__ __launch_bounds__(1024) void sortall_kernel(const int* __restrict__ labels,
                                                       const int* __restrict__ negs,
                                                       int* __restrict__ offs_end,
                                                       int* __restrict__ cntg,
                                                       int* __restrict__ srt_v,
                                                       int* __restrict__ rank) {
    __shared__ int sc[NBUCK];
    int t = threadIdx.x;
    if (t < NBUCK) sc[t] = 0;
    __syncthreads();
    int vs[NSUB / 1024];
    #pragma unroll
    for (int k = 0; k < NSUB / 1024; ++k) {
        int j = k * 1024 + t;
        int v = (j < NPOS) ? max(labels[j], 0) : negs[j - NPOS];
        vs[k] = v;
        atomicAdd(&sc[v >> 8], 1);
    }
    __syncthreads();
    int c = (t < NBUCK) ? sc[t] : 0;
    for (int off = 1; off < NBUCK; off <<= 1) {
        int v2 = (t < NBUCK && t >= off) ? sc[t - off] : 0;
        __syncthreads();
        if (t < NBUCK) sc[t] += v2;
        __syncthreads();
    }
    if (t < NBUCK) { cntg[t] = c; sc[t] -= c; }   // sc = exclusive bucket base
    __syncthreads();
    #pragma unroll
    for (int k = 0; k < NSUB / 1024; ++k) {
        int j = k * 1024 + t;
        int v = vs[k];
        int r = atomicAdd(&sc[v >> 8], 1);
        srt_v[r] = v;
        rank[j] = r;
    }
    __syncthreads();
    if (t < NBUCK) offs_end[t] = sc[t];           // bucket end
}

// ---------------- main1: fused [query, wave-per-rowset] and [W bucket-stream] ----------------
__global__ __launch_bounds__(256) void main1_kernel(const float* __restrict__ Wk,
                                                    const int* __restrict__ srt_v,
                                                    const int* __restrict__ offs_end,
                                                    const int* __restrict__ cnt,
                                                    unsigned short* __restrict__ WT,
                                                    float* __restrict__ norms2,
                                                    const int* __restrict__ indices,
                                                    const float* __restrict__ mask,
                                                    const float* __restrict__ embed,
                                                    float* __restrict__ query,
                                                    unsigned short* __restrict__ qbf) {
    __shared__ __align__(16) unsigned short tile[256][65];   // 33 KB, aliased by query path
    int t = threadIdx.x;
    int w = t >> 6, l = t & 63;

    if (blockIdx.x < BDIM) {
        // ---- query: wave w owns rows [w*32, w*32+32); lane owns cols [l*8, l*8+8) ----
        char* base = (char*)&tile[0][0];
        int*   sidx    = (int*)base;                       // 128 ints
        float* smask   = (float*)(base + 512);             // 128 floats
        float* partial = (float*)(base + 1024);            // [4][512] floats
        float* red     = (float*)(base + 1024 + 8192);     // 4 floats
        float* snorm   = (float*)(base + 1024 + 8192 + 16);// 1 float
        int b = blockIdx.x;
        if (t < LDIM) {
            sidx[t]  = indices[b * LDIM + t];
            smask[t] = mask[b * LDIM + t];
        }
        __syncthreads();
        fv4 a0 = {0.f, 0.f, 0.f, 0.f}, a1 = {0.f, 0.f, 0.f, 0.f};
        #pragma unroll 4
        for (int i = 0; i < 32; ++i) {
            int row = w * 32 + i;
            int idx = sidx[row];
            float m = smask[row];
            const float* rp = &embed[(size_t)idx * DDIM + l * 8];
            fv4 v0 = *(const fv4*)rp;
            fv4 v1 = *(const fv4*)(rp + 4);
            a0 += v0 * m;
            a1 += v1 * m;
        }
        *(fv4*)&partial[w * 512 + l * 8]     = a0;
        *(fv4*)&partial[w * 512 + l * 8 + 4] = a1;
        float msum = 0.f;
        for (int i = 0; i < LDIM; ++i) msum += smask[i];
        __syncthreads();
        int c0 = t * 2;
        float x = partial[c0]       + partial[512 + c0]     + partial[1024 + c0]     + partial[1536 + c0];
        float y = partial[c0 + 1]   + partial[512 + c0 + 1] + partial[1024 + c0 + 1] + partial[1536 + c0 + 1];
        float denom = fmaxf(msum, 1.0f);
        x /= denom; y /= denom;
        float ss = x * x + y * y;
        #pragma unroll
        for (int off = 32; off > 0; off >>= 1) ss += __shfl_xor(ss, off, 64);
        __syncthreads();               // partial reads done before red overwrites? (red is separate region; safe)
        if (l == 0) red[w] = ss;
        __syncthreads();
        if (t == 0) snorm[0] = sqrtf(red[0] + red[1] + red[2] + red[3]);
        __syncthreads();
        float inv = 1.f / fmaxf(snorm[0], 1e-4f);
        x *= inv; y *= inv;
        float2 o = { x, y };
        *(float2*)&query[(size_t)b * DDIM + c0] = o;
        ushort2 ob = { f2bf(x), f2bf(y) };
        *(ushort2*)&qbf[(size_t)b * DDIM + c0] = ob;
    } else {
        // ---- W bucket-stream: block = (bucket g, 64-d tile) ----
        int bt = blockIdx.x - BDIM;
        int g  = bt >> 3;          // 0..511
        int dt = bt & 7;           // 0..7
        int d0 = dt * 64;
        #pragma unroll
        for (int i = 0; i < 16; ++i) {
            int dl = w * 16 + i;
            fv4 v = __builtin_nontemporal_load(
                (const fv4*)&Wk[(size_t)(d0 + dl) * NLAB + g * 256 + l * 4]);
            tile[l * 4 + 0][dl] = f2bf(v[0]);
            tile[l * 4 + 1][dl] = f2bf(v[1]);
            tile[l * 4 + 2][dl] = f2bf(v[2]);
            tile[l * 4 + 3][dl] = f2bf(v[3]);
        }
        __syncthreads();
        int rend = offs_end[g];
        int rbeg = rend - cnt[g];
        for (int r = rbeg + w; r < rend; r += 4) {
            int v = srt_v[r];
            int col = v - g * 256;
            unsigned short h = tile[col][l];
            __builtin_nontemporal_store(h, &WT[(size_t)r * DDIM + d0 + l]);
            float f = bf2f(h);
            float ss = f * f;
            ss += __shfl_xor(ss, 1, 64);  ss += __shfl_xor(ss, 2, 64);
            ss += __shfl_xor(ss, 4, 64);  ss += __shfl_xor(ss, 8, 64);
            ss += __shfl_xor(ss, 16, 64); ss += __shfl_xor(ss, 32, 64);
            if (l == 0) atomicAdd(&norms2[r], ss);
        }
    }
}

// ---------------- main2: fused [neg MFMA GEMM] and [pos dots] ----------------
static __device__ __forceinline__ float score_of(float acc, float nn) {
    float dot = acc / nn;
    dot = fminf(fmaxf(dot, -0.999f), 0.999f);
    return dot * dot / fmaxf(CV - 2.f * dot, EPSV);
}

__global__ __launch_bounds__(256) void main2_kernel(const unsigned short* __restrict__ qbf,
                                                    const float* __restrict__ query,
                                                    const unsigned short* __restrict__ WT,
                                                    const int* __restrict__ rank,
                                                    const float* __restrict__ norms2,
                                                    float* __restrict__ pos_scores,
                                                    float* __restrict__ Zrow) {
    int t = threadIdx.x;
    int w = t >> 6, l = t & 63;
    if (blockIdx.x < (BDIM / 64) * (NNEG / 64)) {
        // ---- negatives: 64x64 tile via MFMA ----
        __shared__ float rowsum[64];
        int bx = blockIdx.x;
        int mt = bx & 15, nt = bx >> 4;
        int wm = w >> 1, wn = w & 1;
        int lr = l & 15, lg = l >> 4;
        int m0 = mt * 64 + wm * 32;
        int n0 = nt * 64 + wn * 32;
        if (t < 64) rowsum[t] = 0.f;
        __syncthreads();

        int rB0 = rank[NPOS + n0 + lr];
        int rB1 = rank[NPOS + n0 + 16 + lr];
        const unsigned short* a0p = qbf + (size_t)(m0 + lr) * DDIM + lg * 8;
        const unsigned short* a1p = qbf + (size_t)(m0 + 16 + lr) * DDIM + lg * 8;
        const unsigned short* b0p = WT + (size_t)rB0 * DDIM + lg * 8;
        const unsigned short* b1p = WT + (size_t)rB1 * DDIM + lg * 8;

        f4v acc00 = {0.f, 0.f, 0.f, 0.f}, acc01 = acc00, acc10 = acc00, acc11 = acc00;
        #pragma unroll
        for (int k0 = 0; k0 < DDIM; k0 += 32) {
            s8v a0 = *(const s8v*)(a0p + k0);
            s8v a1 = *(const s8v*)(a1p + k0);
            s8v b0 = *(const s8v*)(b0p + k0);
            s8v b1 = *(const s8v*)(b1p + k0);
            acc00 = __builtin_amdgcn_mfma_f32_16x16x32_bf16(a0, b0, acc00, 0, 0, 0);
            acc01 = __builtin_amdgcn_mfma_f32_16x16x32_bf16(a0, b1, acc01, 0, 0, 0);
            acc10 = __builtin_amdgcn_mfma_f32_16x16x32_bf16(a1, b0, acc10, 0, 0, 0);
            acc11 = __builtin_amdgcn_mfma_f32_16x16x32_bf16(a1, b1, acc11, 0, 0, 0);
        }

        float nn0 = fmaxf(sqrtf(norms2[rB0]), 1e-4f);
        float nn1 = fmaxf(sqrtf(norms2[rB1]), 1e-4f);
        float s[8];
        #pragma unroll
        for (int i = 0; i < 4; ++i) {
            s[i]     = score_of(acc00[i], nn0) + score_of(acc01[i], nn1);
            s[4 + i] = score_of(acc10[i], nn0) + score_of(acc11[i], nn1);
        }
        #pragma unroll
        for (int i = 0; i < 8; ++i) {
            s[i] += __shfl_xor(s[i], 1, 64);
            s[i] += __shfl_xor(s[i], 2, 64);
            s[i] += __shfl_xor(s[i], 4, 64);
            s[i] += __shfl_xor(s[i], 8, 64);
        }
        if (lr == 0) {
            #pragma unroll
            for (int i = 0; i < 4; ++i) {
                atomicAdd(&rowsum[wm * 32 + lg * 4 + i], s[i]);
                atomicAdd(&rowsum[wm * 32 + 16 + lg * 4 + i], s[4 + i]);
            }
        }
        __syncthreads();
        if (t < 64) atomicAdd(&Zrow[mt * 64 + t], rowsum[t]);
    } else {
        // ---- positives: wave handles one b (16 j) ----
        int px = blockIdx.x - (BDIM / 64) * (NNEG / 64);
        int b = px * 4 + w;
        int j = b * KDIM + (l & 15);
        int r = rank[j];
        int g = l >> 4;
        const unsigned short* wrow = WT + (size_t)r * DDIM + g * 128;
        const float* qrow = query + (size_t)b * DDIM + g * 128;
        float acc = 0.f;
        #pragma unroll
        for (int kk = 0; kk < 128; kk += 8) {
            ushort4 w0 = *(const ushort4*)&wrow[kk];
            ushort4 w1 = *(const ushort4*)&wrow[kk + 4];
            float4 q0 = *(const float4*)&qrow[kk];
            float4 q1 = *(const float4*)&qrow[kk + 4];
            acc += bf2f(w0.x) * q0.x + bf2f(w0.y) * q0.y + bf2f(w0.z) * q0.z + bf2f(w0.w) * q0.w
                 + bf2f(w1.x) * q1.x + bf2f(w1.y) * q1.y + bf2f(w1.z) * q1.z + bf2f(w1.w) * q1.w;
        }
        acc += __shfl_xor(acc, 16, 64);
        acc += __shfl_xor(acc, 32, 64);
        if (l < 16) {
            float nrm = fmaxf(sqrtf(norms2[r]), 1e-4f);
            float dot = fminf(fmaxf(acc / nrm, -0.999f), 0.999f);
            float sc = dot * dot / fmaxf(CV - 2.f * dot, EPSV);
            pos_scores[j] = sc;
            float s = sc;
            s += __shfl_xor(s, 1, 64); s += __shfl_xor(s, 2, 64);
            s += __shfl_xor(s, 4, 64); s += __shfl_xor(s, 8, 64);
            if (l == 0) atomicAdd(&Zrow[b], s);
        }
    }
}

// ---------------- finalize (+writeout via ticket) ----------------
__global__ __launch_bounds__(256) void finalize_kernel(const float* __restrict__ pos_scores,
                                                       const float* __restrict__ label_mask,
                                                       const float* __restrict__ Zrow,
                                                       float* __restrict__ accum,
                                                       int* __restrict__ ticket,
                                                       float* __restrict__ out) {
    int j = blockIdx.x * 256 + threadIdx.x;
    int b = j >> 4;
    float lm = label_mask[j];
    float logZ = logf(Zrow[b] + (float)(KDIM + NNEG) * 1e-8f);
    float v = lm * (logf(pos_scores[j] + 1e-8f) - logZ);
    #pragma unroll
    for (int off = 32; off > 0; off >>= 1) {
        v  += __shfl_down(v, off, 64);
        lm += __shfl_down(lm, off, 64);
    }
    __shared__ float rv[4], rl[4];
    int wid = threadIdx.x >> 6, lane = threadIdx.x & 63;
    if (lane == 0) { rv[wid] = v; rl[wid] = lm; }
    __syncthreads();
    if (threadIdx.x == 0) {
        atomicAdd(&accum[0], rv[0] + rv[1] + rv[2] + rv[3]);
        atomicAdd(&accum[1], rl[0] + rl[1] + rl[2] + rl[3]);
        __threadfence();
        int old = atomicAdd(ticket, 1);
        if (old == (int)gridDim.x - 1) {
            float a = atomicAdd(&accum[0], 0.f);
            float m = atomicAdd(&accum[1], 0.f);
            out[0] = -a / (m + 1e-6f);
        }
    }
}

extern "C" void kernel_launch(void* const* d_in, const int* in_sizes, int n_in,
                              void* d_out, int out_size, void* d_ws, size_t ws_size,
                              hipStream_t stream) {
    const int*   indices    = (const int*)  d_in[0];
    const float* mask       = (const float*)d_in[1];
    const int*   labels     = (const int*)  d_in[2];
    const float* label_mask = (const float*)d_in[3];
    const int*   negs       = (const int*)  d_in[4];
    const float* embed      = (const float*)d_in[5];
    const float* Wk         = (const float*)d_in[6];
    float* out = (float*)d_out;

    // workspace layout (~25 MB)
    unsigned short* WT  = (unsigned short*)d_ws;                    // NSUB*DDIM bf16
    float* query      = (float*)(WT + (size_t)NSUB * DDIM);         // BDIM*DDIM f32
    unsigned short* qbf = (unsigned short*)(query + (size_t)BDIM * DDIM); // BDIM*DDIM bf16
    int*   srt_v      = (int*)(qbf + (size_t)BDIM * DDIM);          // NSUB
    int*   rank       = srt_v + NSUB;                               // NSUB
    float* norms2     = (float*)(rank + NSUB);                      // NSUB
    float* pos_scores = norms2 + NSUB;                              // NPOS
    float* Zrow       = pos_scores + NPOS;                          // BDIM
    float* accum      = Zrow + BDIM;                                // 2
    int*   ticket     = (int*)(accum + 2);                          // 1
    int*   cntg       = ticket + 1;                                 // NBUCK
    int*   offs_end   = cntg + NBUCK;                               // NBUCK

    init_kernel<<<NSUB / 256, 256, 0, stream>>>(norms2, Zrow, accum, ticket);
    sortall_kernel<<<1, 1024, 0, stream>>>(labels, negs, offs_end, cntg, srt_v, rank);
    main1_kernel<<<BDIM + GT_BLOCKS, 256, 0, stream>>>(Wk, srt_v, offs_end, cntg, WT, norms2,
                                                       indices, mask, embed, query, qbf);
    main2_kernel<<<(BDIM / 64) * (NNEG / 64) + NPOS / 64, 256, 0, stream>>>(
        qbf, query, WT, rank, norms2, pos_scores, Zrow);
    finalize_kernel<<<NPOS / 256, 256, 0, stream>>>(pos_scores, label_mask, Zrow,
                                                    accum, ticket, out);
}

// Round 9
// 139.770 us; speedup vs baseline: 1.0991x; 1.0878x over previous
//
#include <hip/hip_runtime.h>
#include <hip/hip_bf16.h>

#define BDIM 1024
#define LDIM 128
#define KDIM 16
#define DDIM 512
#define NLAB 131072
#define NNEG 2048
#define NPOS (BDIM * KDIM)      /* 16384 */
#define NSUB (NPOS + NNEG)      /* 18432 */
#define EPSV 0.1f
#define CV 2.1f
#define NBUCK 512               /* labels per bucket = 256 -> shift 8 */
#define GT_BLOCKS (NBUCK * 8)   /* 4096 W-tile blocks */
#define M1_BLOCKS (BDIM + GT_BLOCKS)  /* 5120 */

typedef __attribute__((ext_vector_type(8))) short s8v;
typedef __attribute__((ext_vector_type(4))) float f4v;
typedef __attribute__((ext_vector_type(4))) float fv4;

static __device__ __forceinline__ unsigned short f2bf(float x) {
    union { float f; unsigned u; } v; v.f = x;
    unsigned r = v.u + 0x7FFF + ((v.u >> 16) & 1);   // RNE
    return (unsigned short)(r >> 16);
}
static __device__ __forceinline__ float bf2f(unsigned short h) {
    return __uint_as_float((unsigned)h << 16);
}

// ---------------- sortinit: block 0 = bucket sort; blocks 1..18 = zero fill ----------------
__global__ __launch_bounds__(1024) void sortinit_kernel(const int* __restrict__ labels,
                                                        const int* __restrict__ negs,
                                                        int* __restrict__ offs_end,
                                                        int* __restrict__ cntg,
                                                        int* __restrict__ srt_v,
                                                        int* __restrict__ rank,
                                                        float* __restrict__ norms2,
                                                        float* __restrict__ Zrow,
                                                        float* __restrict__ accum,
                                                        int* __restrict__ ticket) {
    int t = threadIdx.x;
    if (blockIdx.x != 0) {
        int j = (blockIdx.x - 1) * 1024 + t;   // covers NSUB with 18 blocks
        if (j < NSUB) norms2[j] = 0.f;
        if (j < BDIM) Zrow[j] = 0.f;
        if (j < 2) accum[j] = 0.f;
        if (j == 0) *ticket = 0;
        return;
    }
    __shared__ int sc[NBUCK];
    if (t < NBUCK) sc[t] = 0;
    __syncthreads();
    int vs[NSUB / 1024];
    #pragma unroll
    for (int k = 0; k < NSUB / 1024; ++k) {
        int j = k * 1024 + t;
        int v = (j < NPOS) ? max(labels[j], 0) : negs[j - NPOS];
        vs[k] = v;
        atomicAdd(&sc[v >> 8], 1);
    }
    __syncthreads();
    int c = (t < NBUCK) ? sc[t] : 0;
    for (int off = 1; off < NBUCK; off <<= 1) {
        int v2 = (t < NBUCK && t >= off) ? sc[t - off] : 0;
        __syncthreads();
        if (t < NBUCK) sc[t] += v2;
        __syncthreads();
    }
    if (t < NBUCK) { cntg[t] = c; sc[t] -= c; }   // sc = exclusive bucket base
    __syncthreads();
    #pragma unroll
    for (int k = 0; k < NSUB / 1024; ++k) {
        int j = k * 1024 + t;
        int v = vs[k];
        int r = atomicAdd(&sc[v >> 8], 1);
        srt_v[r] = v;
        rank[j] = r;
    }
    __syncthreads();
    if (t < NBUCK) offs_end[t] = sc[t];           // bucket end
}

// ---------------- main1: INTERLEAVED [query] and [W bucket-stream] ----------------
__global__ __launch_bounds__(256) void main1_kernel(const float* __restrict__ Wk,
                                                    const int* __restrict__ srt_v,
                                                    const int* __restrict__ offs_end,
                                                    const int* __restrict__ cnt,
                                                    unsigned short* __restrict__ WT,
                                                    float* __restrict__ norms2,
                                                    const int* __restrict__ indices,
                                                    const float* __restrict__ mask,
                                                    const float* __restrict__ embed,
                                                    unsigned short* __restrict__ qbf) {
    __shared__ __align__(16) unsigned short tile[256][65];   // 33 KB, aliased by query path
    int t = threadIdx.x;
    int w = t >> 6, l = t & 63;
    int bx = blockIdx.x;

    if (bx % 5 == 0) {
        // ---- query: wave w owns rows [w*32, w*32+32); lane owns cols [l*8, l*8+8) ----
        char* base = (char*)&tile[0][0];
        int*   sidx    = (int*)base;                       // 128 ints
        float* smask   = (float*)(base + 512);             // 128 floats
        float* partial = (float*)(base + 1024);            // [4][512] floats
        float* red     = (float*)(base + 1024 + 8192);     // 4 floats
        float* snorm   = (float*)(base + 1024 + 8192 + 16);// 1 float
        int b = bx / 5;
        if (t < LDIM) {
            sidx[t]  = indices[b * LDIM + t];
            smask[t] = mask[b * LDIM + t];
        }
        __syncthreads();
        fv4 a0 = {0.f, 0.f, 0.f, 0.f}, a1 = {0.f, 0.f, 0.f, 0.f};
        #pragma unroll 4
        for (int i = 0; i < 32; ++i) {
            int row = w * 32 + i;
            int idx = sidx[row];
            float m = smask[row];
            const float* rp = &embed[(size_t)idx * DDIM + l * 8];
            fv4 v0 = *(const fv4*)rp;
            fv4 v1 = *(const fv4*)(rp + 4);
            a0 += v0 * m;
            a1 += v1 * m;
        }
        *(fv4*)&partial[w * 512 + l * 8]     = a0;
        *(fv4*)&partial[w * 512 + l * 8 + 4] = a1;
        float msum = 0.f;
        for (int i = 0; i < LDIM; ++i) msum += smask[i];
        __syncthreads();
        int c0 = t * 2;
        float x = partial[c0]     + partial[512 + c0]     + partial[1024 + c0]     + partial[1536 + c0];
        float y = partial[c0 + 1] + partial[512 + c0 + 1] + partial[1024 + c0 + 1] + partial[1536 + c0 + 1];
        float denom = fmaxf(msum, 1.0f);
        x /= denom; y /= denom;
        float ss = x * x + y * y;
        #pragma unroll
        for (int off = 32; off > 0; off >>= 1) ss += __shfl_xor(ss, off, 64);
        if (l == 0) red[w] = ss;
        __syncthreads();
        if (t == 0) snorm[0] = sqrtf(red[0] + red[1] + red[2] + red[3]);
        __syncthreads();
        float inv = 1.f / fmaxf(snorm[0], 1e-4f);
        x *= inv; y *= inv;
        ushort2 ob = { f2bf(x), f2bf(y) };
        *(ushort2*)&qbf[(size_t)b * DDIM + c0] = ob;
    } else {
        // ---- W bucket-stream: block = (bucket g, 64-d tile) ----
        int bt = bx - bx / 5 - 1;  // 0..4095
        int g  = bt >> 3;          // 0..511
        int dt = bt & 7;           // 0..7
        int d0 = dt * 64;
        #pragma unroll
        for (int i = 0; i < 16; ++i) {
            int dl = w * 16 + i;
            fv4 v = __builtin_nontemporal_load(
                (const fv4*)&Wk[(size_t)(d0 + dl) * NLAB + g * 256 + l * 4]);
            tile[l * 4 + 0][dl] = f2bf(v[0]);
            tile[l * 4 + 1][dl] = f2bf(v[1]);
            tile[l * 4 + 2][dl] = f2bf(v[2]);
            tile[l * 4 + 3][dl] = f2bf(v[3]);
        }
        __syncthreads();
        int rend = offs_end[g];
        int rbeg = rend - cnt[g];
        for (int r = rbeg + w; r < rend; r += 4) {
            int v = srt_v[r];
            int col = v - g * 256;
            unsigned short h = tile[col][l];
            __builtin_nontemporal_store(h, &WT[(size_t)r * DDIM + d0 + l]);
            float f = bf2f(h);
            float ss = f * f;
            ss += __shfl_xor(ss, 1, 64);  ss += __shfl_xor(ss, 2, 64);
            ss += __shfl_xor(ss, 4, 64);  ss += __shfl_xor(ss, 8, 64);
            ss += __shfl_xor(ss, 16, 64); ss += __shfl_xor(ss, 32, 64);
            if (l == 0) atomicAdd(&norms2[r], ss);
        }
    }
}

// ---------------- main2: fused [neg MFMA GEMM] and [pos dots] ----------------
static __device__ __forceinline__ float score_of(float acc, float nn) {
    float dot = acc / nn;
    dot = fminf(fmaxf(dot, -0.999f), 0.999f);
    return dot * dot / fmaxf(CV - 2.f * dot, EPSV);
}

__global__ __launch_bounds__(256) void main2_kernel(const unsigned short* __restrict__ qbf,
                                                    const unsigned short* __restrict__ WT,
                                                    const int* __restrict__ rank,
                                                    const float* __restrict__ norms2,
                                                    float* __restrict__ pos_scores,
                                                    float* __restrict__ Zrow) {
    int t = threadIdx.x;
    int w = t >> 6, l = t & 63;
    if (blockIdx.x < (BDIM / 64) * (NNEG / 64)) {
        // ---- negatives: 64x64 tile via MFMA ----
        __shared__ float rowsum[64];
        int bx = blockIdx.x;
        int mt = bx & 15, nt = bx >> 4;
        int wm = w >> 1, wn = w & 1;
        int lr = l & 15, lg = l >> 4;
        int m0 = mt * 64 + wm * 32;
        int n0 = nt * 64 + wn * 32;
        if (t < 64) rowsum[t] = 0.f;
        __syncthreads();

        int rB0 = rank[NPOS + n0 + lr];
        int rB1 = rank[NPOS + n0 + 16 + lr];
        const unsigned short* a0p = qbf + (size_t)(m0 + lr) * DDIM + lg * 8;
        const unsigned short* a1p = qbf + (size_t)(m0 + 16 + lr) * DDIM + lg * 8;
        const unsigned short* b0p = WT + (size_t)rB0 * DDIM + lg * 8;
        const unsigned short* b1p = WT + (size_t)rB1 * DDIM + lg * 8;

        f4v acc00 = {0.f, 0.f, 0.f, 0.f}, acc01 = acc00, acc10 = acc00, acc11 = acc00;
        #pragma unroll
        for (int k0 = 0; k0 < DDIM; k0 += 32) {
            s8v a0 = *(const s8v*)(a0p + k0);
            s8v a1 = *(const s8v*)(a1p + k0);
            s8v b0 = *(const s8v*)(b0p + k0);
            s8v b1 = *(const s8v*)(b1p + k0);
            acc00 = __builtin_amdgcn_mfma_f32_16x16x32_bf16(a0, b0, acc00, 0, 0, 0);
            acc01 = __builtin_amdgcn_mfma_f32_16x16x32_bf16(a0, b1, acc01, 0, 0, 0);
            acc10 = __builtin_amdgcn_mfma_f32_16x16x32_bf16(a1, b0, acc10, 0, 0, 0);
            acc11 = __builtin_amdgcn_mfma_f32_16x16x32_bf16(a1, b1, acc11, 0, 0, 0);
        }

        float nn0 = fmaxf(sqrtf(norms2[rB0]), 1e-4f);
        float nn1 = fmaxf(sqrtf(norms2[rB1]), 1e-4f);
        float s[8];
        #pragma unroll
        for (int i = 0; i < 4; ++i) {
            s[i]     = score_of(acc00[i], nn0) + score_of(acc01[i], nn1);
            s[4 + i] = score_of(acc10[i], nn0) + score_of(acc11[i], nn1);
        }
        #pragma unroll
        for (int i = 0; i < 8; ++i) {
            s[i] += __shfl_xor(s[i], 1, 64);
            s[i] += __shfl_xor(s[i], 2, 64);
            s[i] += __shfl_xor(s[i], 4, 64);
            s[i] += __shfl_xor(s[i], 8, 64);
        }
        if (lr == 0) {
            #pragma unroll
            for (int i = 0; i < 4; ++i) {
                atomicAdd(&rowsum[wm * 32 + lg * 4 + i], s[i]);
                atomicAdd(&rowsum[wm * 32 + 16 + lg * 4 + i], s[4 + i]);
            }
        }
        __syncthreads();
        if (t < 64) atomicAdd(&Zrow[mt * 64 + t], rowsum[t]);
    } else {
        // ---- positives: wave handles one b (16 j) ----
        int px = blockIdx.x - (BDIM / 64) * (NNEG / 64);
        int b = px * 4 + w;
        int j = b * KDIM + (l & 15);
        int r = rank[j];
        int g = l >> 4;
        const unsigned short* wrow = WT + (size_t)r * DDIM + g * 128;
        const unsigned short* qrow = qbf + (size_t)b * DDIM + g * 128;
        float acc = 0.f;
        #pragma unroll
        for (int kk = 0; kk < 128; kk += 8) {
            ushort4 w0 = *(const ushort4*)&wrow[kk];
            ushort4 w1 = *(const ushort4*)&wrow[kk + 4];
            ushort4 q0 = *(const ushort4*)&qrow[kk];
            ushort4 q1 = *(const ushort4*)&qrow[kk + 4];
            acc += bf2f(w0.x) * bf2f(q0.x) + bf2f(w0.y) * bf2f(q0.y)
                 + bf2f(w0.z) * bf2f(q0.z) + bf2f(w0.w) * bf2f(q0.w)
                 + bf2f(w1.x) * bf2f(q1.x) + bf2f(w1.y) * bf2f(q1.y)
                 + bf2f(w1.z) * bf2f(q1.z) + bf2f(w1.w) * bf2f(q1.w);
        }
        acc += __shfl_xor(acc, 16, 64);
        acc += __shfl_xor(acc, 32, 64);
        if (l < 16) {
            float nrm = fmaxf(sqrtf(norms2[r]), 1e-4f);
            float dot = fminf(fmaxf(acc / nrm, -0.999f), 0.999f);
            float sc = dot * dot / fmaxf(CV - 2.f * dot, EPSV);
            pos_scores[j] = sc;
            float s = sc;
            s += __shfl_xor(s, 1, 64); s += __shfl_xor(s, 2, 64);
            s += __shfl_xor(s, 4, 64); s += __shfl_xor(s, 8, 64);
            if (l == 0) atomicAdd(&Zrow[b], s);
        }
    }
}

// ---------------- finalize (+writeout via ticket) ----------------
__global__ __launch_bounds__(256) void finalize_kernel(const float* __restrict__ pos_scores,
                                                       const float* __restrict__ label_mask,
                                                       const float* __restrict__ Zrow,
                                                       float* __restrict__ accum,
                                                       int* __restrict__ ticket,
                                                       float* __restrict__ out) {
    int j = blockIdx.x * 256 + threadIdx.x;
    int b = j >> 4;
    float lm = label_mask[j];
    float logZ = logf(Zrow[b] + (float)(KDIM + NNEG) * 1e-8f);
    float v = lm * (logf(pos_scores[j] + 1e-8f) - logZ);
    #pragma unroll
    for (int off = 32; off > 0; off >>= 1) {
        v  += __shfl_down(v, off, 64);
        lm += __shfl_down(lm, off, 64);
    }
    __shared__ float rv[4], rl[4];
    int wid = threadIdx.x >> 6, lane = threadIdx.x & 63;
    if (lane == 0) { rv[wid] = v; rl[wid] = lm; }
    __syncthreads();
    if (threadIdx.x == 0) {
        atomicAdd(&accum[0], rv[0] + rv[1] + rv[2] + rv[3]);
        atomicAdd(&accum[1], rl[0] + rl[1] + rl[2] + rl[3]);
        __threadfence();
        int old = atomicAdd(ticket, 1);
        if (old == (int)gridDim.x - 1) {
            float a = atomicAdd(&accum[0], 0.f);
            float m = atomicAdd(&accum[1], 0.f);
            out[0] = -a / (m + 1e-6f);
        }
    }
}

extern "C" void kernel_launch(void* const* d_in, const int* in_sizes, int n_in,
                              void* d_out, int out_size, void* d_ws, size_t ws_size,
                              hipStream_t stream) {
    const int*   indices    = (const int*)  d_in[0];
    const float* mask       = (const float*)d_in[1];
    const int*   labels     = (const int*)  d_in[2];
    const float* label_mask = (const float*)d_in[3];
    const int*   negs       = (const int*)  d_in[4];
    const float* embed      = (const float*)d_in[5];
    const float* Wk         = (const float*)d_in[6];
    float* out = (float*)d_out;

    // workspace layout (~21 MB)
    unsigned short* WT  = (unsigned short*)d_ws;                    // NSUB*DDIM bf16
    unsigned short* qbf = WT + (size_t)NSUB * DDIM;                 // BDIM*DDIM bf16
    int*   srt_v      = (int*)(qbf + (size_t)BDIM * DDIM);          // NSUB
    int*   rank       = srt_v + NSUB;                               // NSUB
    float* norms2     = (float*)(rank + NSUB);                      // NSUB
    float* pos_scores = norms2 + NSUB;                              // NPOS
    float* Zrow       = pos_scores + NPOS;                          // BDIM
    float* accum      = Zrow + BDIM;                                // 2
    int*   ticket     = (int*)(accum + 2);                          // 1
    int*   cntg       = ticket + 1;                                 // NBUCK
    int*   offs_end   = cntg + NBUCK;                               // NBUCK

    sortinit_kernel<<<1 + NSUB / 1024, 1024, 0, stream>>>(labels, negs, offs_end, cntg,
                                                          srt_v, rank, norms2, Zrow,
                                                          accum, ticket);
    main1_kernel<<<M1_BLOCKS, 256, 0, stream>>>(Wk, srt_v, offs_end, cntg, WT, norms2,
                                                indices, mask, embed, qbf);
    main2_kernel<<<(BDIM / 64) * (NNEG / 64) + NPOS / 64, 256, 0, stream>>>(
        qbf, WT, rank, norms2, pos_scores, Zrow);
    finalize_kernel<<<NPOS / 256, 256, 0, stream>>>(pos_scores, label_mask, Zrow,
                                                    accum, ticket, out);
}

// Round 10
// 129.884 us; speedup vs baseline: 1.1827x; 1.0761x over previous
//
#include <hip/hip_runtime.h>
#include <hip/hip_bf16.h>

#define BDIM 1024
#define LDIM 128
#define KDIM 16
#define DDIM 512
#define NLAB 131072
#define NNEG 2048
#define NPOS (BDIM * KDIM)      /* 16384 */
#define NSUB (NPOS + NNEG)      /* 18432 */
#define EPSV 0.1f
#define CV 2.1f
#define NBUCK 512               /* labels per bucket = 256 -> shift 8 */
#define DCHUNKS 16              /* 512 / 32 */
#define GT_BLOCKS (NBUCK * DCHUNKS)   /* 8192 W-tile blocks */
#define M1_BLOCKS (BDIM + GT_BLOCKS)  /* 9216 */

typedef __attribute__((ext_vector_type(8))) short s8v;
typedef __attribute__((ext_vector_type(4))) float f4v;
typedef __attribute__((ext_vector_type(4))) float fv4;

static __device__ __forceinline__ unsigned short f2bf(float x) {
    union { float f; unsigned u; } v; v.f = x;
    unsigned r = v.u + 0x7FFF + ((v.u >> 16) & 1);   // RNE
    return (unsigned short)(r >> 16);
}
static __device__ __forceinline__ float bf2f(unsigned short h) {
    return __uint_as_float((unsigned)h << 16);
}

// ---------------- sortinit: block 0 = bucket sort; blocks 1..18 = zero fill ----------------
__global__ __launch_bounds__(1024) void sortinit_kernel(const int* __restrict__ labels,
                                                        const int* __restrict__ negs,
                                                        int* __restrict__ offs_end,
                                                        int* __restrict__ cntg,
                                                        int* __restrict__ srt_v,
                                                        int* __restrict__ rank,
                                                        float* __restrict__ norms2,
                                                        float* __restrict__ Zrow,
                                                        float* __restrict__ accum,
                                                        int* __restrict__ ticket) {
    int t = threadIdx.x;
    if (blockIdx.x != 0) {
        int j = (blockIdx.x - 1) * 1024 + t;   // covers NSUB with 18 blocks
        if (j < NSUB) norms2[j] = 0.f;
        if (j < BDIM) Zrow[j] = 0.f;
        if (j < 2) accum[j] = 0.f;
        if (j == 0) *ticket = 0;
        return;
    }
    __shared__ int sc[NBUCK];
    if (t < NBUCK) sc[t] = 0;
    __syncthreads();
    int vs[NSUB / 1024];
    #pragma unroll
    for (int k = 0; k < NSUB / 1024; ++k) {
        int j = k * 1024 + t;
        int v = (j < NPOS) ? max(labels[j], 0) : negs[j - NPOS];
        vs[k] = v;
        atomicAdd(&sc[v >> 8], 1);
    }
    __syncthreads();
    int c = (t < NBUCK) ? sc[t] : 0;
    for (int off = 1; off < NBUCK; off <<= 1) {
        int v2 = (t < NBUCK && t >= off) ? sc[t - off] : 0;
        __syncthreads();
        if (t < NBUCK) sc[t] += v2;
        __syncthreads();
    }
    if (t < NBUCK) { cntg[t] = c; sc[t] -= c; }   // sc = exclusive bucket base
    __syncthreads();
    #pragma unroll
    for (int k = 0; k < NSUB / 1024; ++k) {
        int j = k * 1024 + t;
        int v = vs[k];
        int r = atomicAdd(&sc[v >> 8], 1);
        srt_v[r] = v;
        rank[j] = r;
    }
    __syncthreads();
    if (t < NBUCK) offs_end[t] = sc[t];           // bucket end
}

// ---------------- main1: INTERLEAVED [query] and [W bucket-stream, 32-d tiles] ----------------
__global__ __launch_bounds__(256) void main1_kernel(const float* __restrict__ Wk,
                                                    const int* __restrict__ srt_v,
                                                    const int* __restrict__ offs_end,
                                                    const int* __restrict__ cnt,
                                                    unsigned short* __restrict__ WT,
                                                    float* __restrict__ norms2,
                                                    const int* __restrict__ indices,
                                                    const float* __restrict__ mask,
                                                    const float* __restrict__ embed,
                                                    unsigned short* __restrict__ qbf) {
    __shared__ __align__(16) unsigned short tile[256][33];   // 16.9 KB -> 8 blocks/CU
    int t = threadIdx.x;
    int w = t >> 6, l = t & 63;
    int bx = blockIdx.x;

    if (bx % 9 == 0) {
        // ---- query: wave w owns rows [w*32, w*32+32); lane owns cols [l*8, l*8+8) ----
        char* base = (char*)&tile[0][0];
        int*   sidx    = (int*)base;                       // 128 ints
        float* smask   = (float*)(base + 512);             // 128 floats
        float* partial = (float*)(base + 1024);            // [4][512] floats
        float* red     = (float*)(base + 1024 + 8192);     // 4 floats
        float* snorm   = (float*)(base + 1024 + 8192 + 16);// 1 float
        int b = bx / 9;
        if (t < LDIM) {
            sidx[t]  = indices[b * LDIM + t];
            smask[t] = mask[b * LDIM + t];
        }
        __syncthreads();
        fv4 a0 = {0.f, 0.f, 0.f, 0.f}, a1 = {0.f, 0.f, 0.f, 0.f};
        #pragma unroll 4
        for (int i = 0; i < 32; ++i) {
            int row = w * 32 + i;
            int idx = sidx[row];
            float m = smask[row];
            const float* rp = &embed[(size_t)idx * DDIM + l * 8];
            fv4 v0 = *(const fv4*)rp;
            fv4 v1 = *(const fv4*)(rp + 4);
            a0 += v0 * m;
            a1 += v1 * m;
        }
        *(fv4*)&partial[w * 512 + l * 8]     = a0;
        *(fv4*)&partial[w * 512 + l * 8 + 4] = a1;
        float msum = 0.f;
        for (int i = 0; i < LDIM; ++i) msum += smask[i];
        __syncthreads();
        int c0 = t * 2;
        float x = partial[c0]     + partial[512 + c0]     + partial[1024 + c0]     + partial[1536 + c0];
        float y = partial[c0 + 1] + partial[512 + c0 + 1] + partial[1024 + c0 + 1] + partial[1536 + c0 + 1];
        float denom = fmaxf(msum, 1.0f);
        x /= denom; y /= denom;
        float ss = x * x + y * y;
        #pragma unroll
        for (int off = 32; off > 0; off >>= 1) ss += __shfl_xor(ss, off, 64);
        if (l == 0) red[w] = ss;
        __syncthreads();
        if (t == 0) snorm[0] = sqrtf(red[0] + red[1] + red[2] + red[3]);
        __syncthreads();
        float inv = 1.f / fmaxf(snorm[0], 1e-4f);
        x *= inv; y *= inv;
        ushort2 ob = { f2bf(x), f2bf(y) };
        *(ushort2*)&qbf[(size_t)b * DDIM + c0] = ob;
    } else {
        // ---- W bucket-stream: block = (bucket g, 32-d chunk) ----
        int bt = bx - bx / 9 - 1;   // 0..8191
        int g  = bt >> 4;           // 0..511
        int dc = bt & 15;           // 0..15
        int d0 = dc * 32;
        // read: 32 d-rows; wave w rows w*8+i; lane reads float4 at label col l*4 (coalesced 1 KB/row)
        #pragma unroll
        for (int i = 0; i < 8; ++i) {
            int dl = w * 8 + i;
            fv4 v = __builtin_nontemporal_load(
                (const fv4*)&Wk[(size_t)(d0 + dl) * NLAB + g * 256 + l * 4]);
            tile[l * 4 + 0][dl] = f2bf(v[0]);
            tile[l * 4 + 1][dl] = f2bf(v[1]);
            tile[l * 4 + 2][dl] = f2bf(v[2]);
            tile[l * 4 + 3][dl] = f2bf(v[3]);
        }
        __syncthreads();
        // write: 2 rows per wave-iter; lane group (l>>5) picks row, (l&31) picks d
        int rend = offs_end[g];
        int rbeg = rend - cnt[g];
        int ld = l & 31, lh = l >> 5;
        for (int r = rbeg + w * 2 + lh; r < rend; r += 8) {
            int v = srt_v[r];
            int col = v - g * 256;
            unsigned short h = tile[col][ld];
            __builtin_nontemporal_store(h, &WT[(size_t)r * DDIM + d0 + ld]);
            float f = bf2f(h);
            float ss = f * f;
            ss += __shfl_xor(ss, 1, 64);  ss += __shfl_xor(ss, 2, 64);
            ss += __shfl_xor(ss, 4, 64);  ss += __shfl_xor(ss, 8, 64);
            ss += __shfl_xor(ss, 16, 64);
            if (ld == 0) atomicAdd(&norms2[r], ss);
        }
    }
}

// ---------------- main2: fused [neg MFMA GEMM] and [pos dots] ----------------
static __device__ __forceinline__ float score_of(float acc, float nn) {
    float dot = acc / nn;
    dot = fminf(fmaxf(dot, -0.999f), 0.999f);
    return dot * dot / fmaxf(CV - 2.f * dot, EPSV);
}

__global__ __launch_bounds__(256) void main2_kernel(const unsigned short* __restrict__ qbf,
                                                    const unsigned short* __restrict__ WT,
                                                    const int* __restrict__ rank,
                                                    const float* __restrict__ norms2,
                                                    float* __restrict__ pos_scores,
                                                    float* __restrict__ Zrow) {
    int t = threadIdx.x;
    int w = t >> 6, l = t & 63;
    if (blockIdx.x < (BDIM / 64) * (NNEG / 64)) {
        // ---- negatives: 64x64 tile via MFMA ----
        __shared__ float rowsum[64];
        int bx = blockIdx.x;
        int mt = bx & 15, nt = bx >> 4;
        int wm = w >> 1, wn = w & 1;
        int lr = l & 15, lg = l >> 4;
        int m0 = mt * 64 + wm * 32;
        int n0 = nt * 64 + wn * 32;
        if (t < 64) rowsum[t] = 0.f;
        __syncthreads();

        int rB0 = rank[NPOS + n0 + lr];
        int rB1 = rank[NPOS + n0 + 16 + lr];
        const unsigned short* a0p = qbf + (size_t)(m0 + lr) * DDIM + lg * 8;
        const unsigned short* a1p = qbf + (size_t)(m0 + 16 + lr) * DDIM + lg * 8;
        const unsigned short* b0p = WT + (size_t)rB0 * DDIM + lg * 8;
        const unsigned short* b1p = WT + (size_t)rB1 * DDIM + lg * 8;

        f4v acc00 = {0.f, 0.f, 0.f, 0.f}, acc01 = acc00, acc10 = acc00, acc11 = acc00;
        #pragma unroll
        for (int k0 = 0; k0 < DDIM; k0 += 32) {
            s8v a0 = *(const s8v*)(a0p + k0);
            s8v a1 = *(const s8v*)(a1p + k0);
            s8v b0 = *(const s8v*)(b0p + k0);
            s8v b1 = *(const s8v*)(b1p + k0);
            acc00 = __builtin_amdgcn_mfma_f32_16x16x32_bf16(a0, b0, acc00, 0, 0, 0);
            acc01 = __builtin_amdgcn_mfma_f32_16x16x32_bf16(a0, b1, acc01, 0, 0, 0);
            acc10 = __builtin_amdgcn_mfma_f32_16x16x32_bf16(a1, b0, acc10, 0, 0, 0);
            acc11 = __builtin_amdgcn_mfma_f32_16x16x32_bf16(a1, b1, acc11, 0, 0, 0);
        }

        float nn0 = fmaxf(sqrtf(norms2[rB0]), 1e-4f);
        float nn1 = fmaxf(sqrtf(norms2[rB1]), 1e-4f);
        float s[8];
        #pragma unroll
        for (int i = 0; i < 4; ++i) {
            s[i]     = score_of(acc00[i], nn0) + score_of(acc01[i], nn1);
            s[4 + i] = score_of(acc10[i], nn0) + score_of(acc11[i], nn1);
        }
        #pragma unroll
        for (int i = 0; i < 8; ++i) {
            s[i] += __shfl_xor(s[i], 1, 64);
            s[i] += __shfl_xor(s[i], 2, 64);
            s[i] += __shfl_xor(s[i], 4, 64);
            s[i] += __shfl_xor(s[i], 8, 64);
        }
        if (lr == 0) {
            #pragma unroll
            for (int i = 0; i < 4; ++i) {
                atomicAdd(&rowsum[wm * 32 + lg * 4 + i], s[i]);
                atomicAdd(&rowsum[wm * 32 + 16 + lg * 4 + i], s[4 + i]);
            }
        }
        __syncthreads();
        if (t < 64) atomicAdd(&Zrow[mt * 64 + t], rowsum[t]);
    } else {
        // ---- positives: wave handles one b (16 j) ----
        int px = blockIdx.x - (BDIM / 64) * (NNEG / 64);
        int b = px * 4 + w;
        int j = b * KDIM + (l & 15);
        int r = rank[j];
        int g = l >> 4;
        const unsigned short* wrow = WT + (size_t)r * DDIM + g * 128;
        const unsigned short* qrow = qbf + (size_t)b * DDIM + g * 128;
        float acc = 0.f;
        #pragma unroll
        for (int kk = 0; kk < 128; kk += 8) {
            ushort4 w0 = *(const ushort4*)&wrow[kk];
            ushort4 w1 = *(const ushort4*)&wrow[kk + 4];
            ushort4 q0 = *(const ushort4*)&qrow[kk];
            ushort4 q1 = *(const ushort4*)&qrow[kk + 4];
            acc += bf2f(w0.x) * bf2f(q0.x) + bf2f(w0.y) * bf2f(q0.y)
                 + bf2f(w0.z) * bf2f(q0.z) + bf2f(w0.w) * bf2f(q0.w)
                 + bf2f(w1.x) * bf2f(q1.x) + bf2f(w1.y) * bf2f(q1.y)
                 + bf2f(w1.z) * bf2f(q1.z) + bf2f(w1.w) * bf2f(q1.w);
        }
        acc += __shfl_xor(acc, 16, 64);
        acc += __shfl_xor(acc, 32, 64);
        if (l < 16) {
            float nrm = fmaxf(sqrtf(norms2[r]), 1e-4f);
            float dot = fminf(fmaxf(acc / nrm, -0.999f), 0.999f);
            float sc = dot * dot / fmaxf(CV - 2.f * dot, EPSV);
            pos_scores[j] = sc;
            float s = sc;
            s += __shfl_xor(s, 1, 64); s += __shfl_xor(s, 2, 64);
            s += __shfl_xor(s, 4, 64); s += __shfl_xor(s, 8, 64);
            if (l == 0) atomicAdd(&Zrow[b], s);
        }
    }
}

// ---------------- finalize (+writeout via ticket) ----------------
__global__ __launch_bounds__(256) void finalize_kernel(const float* __restrict__ pos_scores,
                                                       const float* __restrict__ label_mask,
                                                       const float* __restrict__ Zrow,
                                                       float* __restrict__ accum,
                                                       int* __restrict__ ticket,
                                                       float* __restrict__ out) {
    int j = blockIdx.x * 256 + threadIdx.x;
    int b = j >> 4;
    float lm = label_mask[j];
    float logZ = logf(Zrow[b] + (float)(KDIM + NNEG) * 1e-8f);
    float v = lm * (logf(pos_scores[j] + 1e-8f) - logZ);
    #pragma unroll
    for (int off = 32; off > 0; off >>= 1) {
        v  += __shfl_down(v, off, 64);
        lm += __shfl_down(lm, off, 64);
    }
    __shared__ float rv[4], rl[4];
    int wid = threadIdx.x >> 6, lane = threadIdx.x & 63;
    if (lane == 0) { rv[wid] = v; rl[wid] = lm; }
    __syncthreads();
    if (threadIdx.x == 0) {
        atomicAdd(&accum[0], rv[0] + rv[1] + rv[2] + rv[3]);
        atomicAdd(&accum[1], rl[0] + rl[1] + rl[2] + rl[3]);
        __threadfence();
        int old = atomicAdd(ticket, 1);
        if (old == (int)gridDim.x - 1) {
            float a = atomicAdd(&accum[0], 0.f);
            float m = atomicAdd(&accum[1], 0.f);
            out[0] = -a / (m + 1e-6f);
        }
    }
}

extern "C" void kernel_launch(void* const* d_in, const int* in_sizes, int n_in,
                              void* d_out, int out_size, void* d_ws, size_t ws_size,
                              hipStream_t stream) {
    const int*   indices    = (const int*)  d_in[0];
    const float* mask       = (const float*)d_in[1];
    const int*   labels     = (const int*)  d_in[2];
    const float* label_mask = (const float*)d_in[3];
    const int*   negs       = (const int*)  d_in[4];
    const float* embed      = (const float*)d_in[5];
    const float* Wk         = (const float*)d_in[6];
    float* out = (float*)d_out;

    // workspace layout (~21 MB)
    unsigned short* WT  = (unsigned short*)d_ws;                    // NSUB*DDIM bf16
    unsigned short* qbf = WT + (size_t)NSUB * DDIM;                 // BDIM*DDIM bf16
    int*   srt_v      = (int*)(qbf + (size_t)BDIM * DDIM);          // NSUB
    int*   rank       = srt_v + NSUB;                               // NSUB
    float* norms2     = (float*)(rank + NSUB);                      // NSUB
    float* pos_scores = norms2 + NSUB;                              // NPOS
    float* Zrow       = pos_scores + NPOS;                          // BDIM
    float* accum      = Zrow + BDIM;                                // 2
    int*   ticket     = (int*)(accum + 2);                          // 1
    int*   cntg       = ticket + 1;                                 // NBUCK
    int*   offs_end   = cntg + NBUCK;                               // NBUCK

    sortinit_kernel<<<1 + NSUB / 1024, 1024, 0, stream>>>(labels, negs, offs_end, cntg,
                                                          srt_v, rank, norms2, Zrow,
                                                          accum, ticket);
    main1_kernel<<<M1_BLOCKS, 256, 0, stream>>>(Wk, srt_v, offs_end, cntg, WT, norms2,
                                                indices, mask, embed, qbf);
    main2_kernel<<<(BDIM / 64) * (NNEG / 64) + NPOS / 64, 256, 0, stream>>>(
        qbf, WT, rank, norms2, pos_scores, Zrow);
    finalize_kernel<<<NPOS / 256, 256, 0, stream>>>(pos_scores, label_mask, Zrow,
                                                    accum, ticket, out);
}

// Round 11
// 129.806 us; speedup vs baseline: 1.1835x; 1.0006x over previous
//
#include <hip/hip_runtime.h>
#include <hip/hip_bf16.h>

#define BDIM 1024
#define LDIM 128
#define KDIM 16
#define DDIM 512
#define NLAB 131072
#define NNEG 2048
#define NPOS (BDIM * KDIM)      /* 16384 */
#define NSUB (NPOS + NNEG)      /* 18432 */
#define EPSV 0.1f
#define CV 2.1f
#define NBUCK 512               /* labels per bucket = 256 -> shift 8 */
#define DCHUNKS 16              /* 512 / 32 */
#define GT_BLOCKS (NBUCK * DCHUNKS)   /* 8192 W-tile blocks */
#define M1_BLOCKS (BDIM + GT_BLOCKS)  /* 9216 */

typedef __attribute__((ext_vector_type(8))) short s8v;
typedef __attribute__((ext_vector_type(4))) float f4v;
typedef __attribute__((ext_vector_type(4))) float fv4;

static __device__ __forceinline__ unsigned short f2bf(float x) {
    union { float f; unsigned u; } v; v.f = x;
    unsigned r = v.u + 0x7FFF + ((v.u >> 16) & 1);   // RNE
    return (unsigned short)(r >> 16);
}
static __device__ __forceinline__ float bf2f(unsigned short h) {
    return __uint_as_float((unsigned)h << 16);
}

// ---------------- sortinit: block 0 = bucket sort; blocks 1..18 = zero fill ----------------
__global__ __launch_bounds__(1024) void sortinit_kernel(const int* __restrict__ labels,
                                                        const int* __restrict__ negs,
                                                        int* __restrict__ offs_end,
                                                        int* __restrict__ cntg,
                                                        int* __restrict__ srt_v,
                                                        int* __restrict__ rank,
                                                        float* __restrict__ norms2,
                                                        float* __restrict__ Zrow,
                                                        float* __restrict__ accum,
                                                        int* __restrict__ ticket) {
    int t = threadIdx.x;
    if (blockIdx.x != 0) {
        int j = (blockIdx.x - 1) * 1024 + t;   // covers NSUB with 18 blocks
        if (j < NSUB) norms2[j] = 0.f;
        if (j < BDIM) Zrow[j] = 0.f;
        if (j < 2) accum[j] = 0.f;
        if (j == 0) *ticket = 0;
        return;
    }
    __shared__ int sc[NBUCK];
    if (t < NBUCK) sc[t] = 0;
    __syncthreads();
    int vs[NSUB / 1024];
    #pragma unroll
    for (int k = 0; k < NSUB / 1024; ++k) {
        int j = k * 1024 + t;
        int v = (j < NPOS) ? max(labels[j], 0) : negs[j - NPOS];
        vs[k] = v;
        atomicAdd(&sc[v >> 8], 1);
    }
    __syncthreads();
    int c = (t < NBUCK) ? sc[t] : 0;
    for (int off = 1; off < NBUCK; off <<= 1) {
        int v2 = (t < NBUCK && t >= off) ? sc[t - off] : 0;
        __syncthreads();
        if (t < NBUCK) sc[t] += v2;
        __syncthreads();
    }
    if (t < NBUCK) { cntg[t] = c; sc[t] -= c; }   // sc = exclusive bucket base
    __syncthreads();
    #pragma unroll
    for (int k = 0; k < NSUB / 1024; ++k) {
        int j = k * 1024 + t;
        int v = vs[k];
        int r = atomicAdd(&sc[v >> 8], 1);
        srt_v[r] = v;
        rank[j] = r;
    }
    __syncthreads();
    if (t < NBUCK) offs_end[t] = sc[t];           // bucket end
}

// ---------------- main1: INTERLEAVED [query] and [W bucket-stream, 32-d tiles] ----------------
__global__ __launch_bounds__(256) void main1_kernel(const float* __restrict__ Wk,
                                                    const int* __restrict__ srt_v,
                                                    const int* __restrict__ offs_end,
                                                    const int* __restrict__ cnt,
                                                    unsigned short* __restrict__ WT,
                                                    float* __restrict__ norms2,
                                                    const int* __restrict__ indices,
                                                    const float* __restrict__ mask,
                                                    const float* __restrict__ embed,
                                                    unsigned short* __restrict__ qbf) {
    __shared__ __align__(16) unsigned short tile[256][33];   // 16.9 KB -> 8 blocks/CU
    int t = threadIdx.x;
    int w = t >> 6, l = t & 63;
    int bx = blockIdx.x;

    if (bx % 9 == 0) {
        // ---- query: wave w owns rows [w*32, w*32+32); lane owns cols [l*8, l*8+8) ----
        char* base = (char*)&tile[0][0];
        int*   sidx    = (int*)base;                       // 128 ints
        float* smask   = (float*)(base + 512);             // 128 floats
        float* partial = (float*)(base + 1024);            // [4][512] floats
        float* red     = (float*)(base + 1024 + 8192);     // 4 floats
        float* snorm   = (float*)(base + 1024 + 8192 + 16);// 1 float
        int b = bx / 9;
        if (t < LDIM) {
            sidx[t]  = indices[b * LDIM + t];
            smask[t] = mask[b * LDIM + t];
        }
        __syncthreads();
        fv4 a0 = {0.f, 0.f, 0.f, 0.f}, a1 = {0.f, 0.f, 0.f, 0.f};
        #pragma unroll 4
        for (int i = 0; i < 32; ++i) {
            int row = w * 32 + i;
            int idx = sidx[row];
            float m = smask[row];
            const float* rp = &embed[(size_t)idx * DDIM + l * 8];
            fv4 v0 = *(const fv4*)rp;
            fv4 v1 = *(const fv4*)(rp + 4);
            a0 += v0 * m;
            a1 += v1 * m;
        }
        *(fv4*)&partial[w * 512 + l * 8]     = a0;
        *(fv4*)&partial[w * 512 + l * 8 + 4] = a1;
        float msum = 0.f;
        for (int i = 0; i < LDIM; ++i) msum += smask[i];
        __syncthreads();
        int c0 = t * 2;
        float x = partial[c0]     + partial[512 + c0]     + partial[1024 + c0]     + partial[1536 + c0];
        float y = partial[c0 + 1] + partial[512 + c0 + 1] + partial[1024 + c0 + 1] + partial[1536 + c0 + 1];
        float denom = fmaxf(msum, 1.0f);
        x /= denom; y /= denom;
        float ss = x * x + y * y;
        #pragma unroll
        for (int off = 32; off > 0; off >>= 1) ss += __shfl_xor(ss, off, 64);
        if (l == 0) red[w] = ss;
        __syncthreads();
        if (t == 0) snorm[0] = sqrtf(red[0] + red[1] + red[2] + red[3]);
        __syncthreads();
        float inv = 1.f / fmaxf(snorm[0], 1e-4f);
        x *= inv; y *= inv;
        ushort2 ob = { f2bf(x), f2bf(y) };
        *(ushort2*)&qbf[(size_t)b * DDIM + c0] = ob;
    } else {
        // ---- W bucket-stream: block = (bucket g, 32-d chunk) ----
        int bt = bx - bx / 9 - 1;   // 0..8191
        int g  = bt >> 4;           // 0..511
        int dc = bt & 15;           // 0..15
        int d0 = dc * 32;
        // read: 32 d-rows; wave w rows w*8+i; lane reads float4 at label col l*4 (coalesced 1 KB/row)
        #pragma unroll
        for (int i = 0; i < 8; ++i) {
            int dl = w * 8 + i;
            fv4 v = __builtin_nontemporal_load(
                (const fv4*)&Wk[(size_t)(d0 + dl) * NLAB + g * 256 + l * 4]);
            tile[l * 4 + 0][dl] = f2bf(v[0]);
            tile[l * 4 + 1][dl] = f2bf(v[1]);
            tile[l * 4 + 2][dl] = f2bf(v[2]);
            tile[l * 4 + 3][dl] = f2bf(v[3]);
        }
        __syncthreads();
        // write: CACHED stores (main2 re-reads WT from L2) — 2 rows per wave-iter
        int rend = offs_end[g];
        int rbeg = rend - cnt[g];
        int ld = l & 31, lh = l >> 5;
        for (int r = rbeg + w * 2 + lh; r < rend; r += 8) {
            int v = srt_v[r];
            int col = v - g * 256;
            unsigned short h = tile[col][ld];
            WT[(size_t)r * DDIM + d0 + ld] = h;
            float f = bf2f(h);
            float ss = f * f;
            ss += __shfl_xor(ss, 1, 64);  ss += __shfl_xor(ss, 2, 64);
            ss += __shfl_xor(ss, 4, 64);  ss += __shfl_xor(ss, 8, 64);
            ss += __shfl_xor(ss, 16, 64);
            if (ld == 0) atomicAdd(&norms2[r], ss);
        }
    }
}

// ---------------- main2: fused [neg MFMA GEMM] and [pos dots] ----------------
static __device__ __forceinline__ float score_of(float acc, float nn) {
    float dot = acc / nn;
    dot = fminf(fmaxf(dot, -0.999f), 0.999f);
    return dot * dot / fmaxf(CV - 2.f * dot, EPSV);
}

__global__ __launch_bounds__(256) void main2_kernel(const unsigned short* __restrict__ qbf,
                                                    const unsigned short* __restrict__ WT,
                                                    const int* __restrict__ rank,
                                                    const float* __restrict__ norms2,
                                                    float* __restrict__ pos_scores,
                                                    float* __restrict__ Zrow) {
    int t = threadIdx.x;
    int w = t >> 6, l = t & 63;
    if (blockIdx.x < (BDIM / 64) * (NNEG / 64)) {
        // ---- negatives: 64x64 tile via MFMA ----
        __shared__ float rowsum[64];
        int bx = blockIdx.x;
        int mt = bx & 15, nt = bx >> 4;
        int wm = w >> 1, wn = w & 1;
        int lr = l & 15, lg = l >> 4;
        int m0 = mt * 64 + wm * 32;
        int n0 = nt * 64 + wn * 32;
        if (t < 64) rowsum[t] = 0.f;
        __syncthreads();

        int rB0 = rank[NPOS + n0 + lr];
        int rB1 = rank[NPOS + n0 + 16 + lr];
        const unsigned short* a0p = qbf + (size_t)(m0 + lr) * DDIM + lg * 8;
        const unsigned short* a1p = qbf + (size_t)(m0 + 16 + lr) * DDIM + lg * 8;
        const unsigned short* b0p = WT + (size_t)rB0 * DDIM + lg * 8;
        const unsigned short* b1p = WT + (size_t)rB1 * DDIM + lg * 8;

        f4v acc00 = {0.f, 0.f, 0.f, 0.f}, acc01 = acc00, acc10 = acc00, acc11 = acc00;
        #pragma unroll
        for (int k0 = 0; k0 < DDIM; k0 += 32) {
            s8v a0 = *(const s8v*)(a0p + k0);
            s8v a1 = *(const s8v*)(a1p + k0);
            s8v b0 = *(const s8v*)(b0p + k0);
            s8v b1 = *(const s8v*)(b1p + k0);
            acc00 = __builtin_amdgcn_mfma_f32_16x16x32_bf16(a0, b0, acc00, 0, 0, 0);
            acc01 = __builtin_amdgcn_mfma_f32_16x16x32_bf16(a0, b1, acc01, 0, 0, 0);
            acc10 = __builtin_amdgcn_mfma_f32_16x16x32_bf16(a1, b0, acc10, 0, 0, 0);
            acc11 = __builtin_amdgcn_mfma_f32_16x16x32_bf16(a1, b1, acc11, 0, 0, 0);
        }

        float nn0 = fmaxf(sqrtf(norms2[rB0]), 1e-4f);
        float nn1 = fmaxf(sqrtf(norms2[rB1]), 1e-4f);
        float s[8];
        #pragma unroll
        for (int i = 0; i < 4; ++i) {
            s[i]     = score_of(acc00[i], nn0) + score_of(acc01[i], nn1);
            s[4 + i] = score_of(acc10[i], nn0) + score_of(acc11[i], nn1);
        }
        #pragma unroll
        for (int i = 0; i < 8; ++i) {
            s[i] += __shfl_xor(s[i], 1, 64);
            s[i] += __shfl_xor(s[i], 2, 64);
            s[i] += __shfl_xor(s[i], 4, 64);
            s[i] += __shfl_xor(s[i], 8, 64);
        }
        if (lr == 0) {
            #pragma unroll
            for (int i = 0; i < 4; ++i) {
                atomicAdd(&rowsum[wm * 32 + lg * 4 + i], s[i]);
                atomicAdd(&rowsum[wm * 32 + 16 + lg * 4 + i], s[4 + i]);
            }
        }
        __syncthreads();
        if (t < 64) atomicAdd(&Zrow[mt * 64 + t], rowsum[t]);
    } else {
        // ---- positives: wave handles one b (16 j) ----
        int px = blockIdx.x - (BDIM / 64) * (NNEG / 64);
        int b = px * 4 + w;
        int j = b * KDIM + (l & 15);
        int r = rank[j];
        int g = l >> 4;
        const unsigned short* wrow = WT + (size_t)r * DDIM + g * 128;
        const unsigned short* qrow = qbf + (size_t)b * DDIM + g * 128;
        float acc = 0.f;
        #pragma unroll
        for (int kk = 0; kk < 128; kk += 8) {
            ushort4 w0 = *(const ushort4*)&wrow[kk];
            ushort4 w1 = *(const ushort4*)&wrow[kk + 4];
            ushort4 q0 = *(const ushort4*)&qrow[kk];
            ushort4 q1 = *(const ushort4*)&qrow[kk + 4];
            acc += bf2f(w0.x) * bf2f(q0.x) + bf2f(w0.y) * bf2f(q0.y)
                 + bf2f(w0.z) * bf2f(q0.z) + bf2f(w0.w) * bf2f(q0.w)
                 + bf2f(w1.x) * bf2f(q1.x) + bf2f(w1.y) * bf2f(q1.y)
                 + bf2f(w1.z) * bf2f(q1.z) + bf2f(w1.w) * bf2f(q1.w);
        }
        acc += __shfl_xor(acc, 16, 64);
        acc += __shfl_xor(acc, 32, 64);
        if (l < 16) {
            float nrm = fmaxf(sqrtf(norms2[r]), 1e-4f);
            float dot = fminf(fmaxf(acc / nrm, -0.999f), 0.999f);
            float sc = dot * dot / fmaxf(CV - 2.f * dot, EPSV);
            pos_scores[j] = sc;
            float s = sc;
            s += __shfl_xor(s, 1, 64); s += __shfl_xor(s, 2, 64);
            s += __shfl_xor(s, 4, 64); s += __shfl_xor(s, 8, 64);
            if (l == 0) atomicAdd(&Zrow[b], s);
        }
    }
}

// ---------------- finalize (+writeout via ticket) ----------------
__global__ __launch_bounds__(256) void finalize_kernel(const float* __restrict__ pos_scores,
                                                       const float* __restrict__ label_mask,
                                                       const float* __restrict__ Zrow,
                                                       float* __restrict__ accum,
                                                       int* __restrict__ ticket,
                                                       float* __restrict__ out) {
    int j = blockIdx.x * 256 + threadIdx.x;
    int b = j >> 4;
    float lm = label_mask[j];
    float logZ = logf(Zrow[b] + (float)(KDIM + NNEG) * 1e-8f);
    float v = lm * (logf(pos_scores[j] + 1e-8f) - logZ);
    #pragma unroll
    for (int off = 32; off > 0; off >>= 1) {
        v  += __shfl_down(v, off, 64);
        lm += __shfl_down(lm, off, 64);
    }
    __shared__ float rv[4], rl[4];
    int wid = threadIdx.x >> 6, lane = threadIdx.x & 63;
    if (lane == 0) { rv[wid] = v; rl[wid] = lm; }
    __syncthreads();
    if (threadIdx.x == 0) {
        atomicAdd(&accum[0], rv[0] + rv[1] + rv[2] + rv[3]);
        atomicAdd(&accum[1], rl[0] + rl[1] + rl[2] + rl[3]);
        __threadfence();
        int old = atomicAdd(ticket, 1);
        if (old == (int)gridDim.x - 1) {
            float a = atomicAdd(&accum[0], 0.f);
            float m = atomicAdd(&accum[1], 0.f);
            out[0] = -a / (m + 1e-6f);
        }
    }
}

extern "C" void kernel_launch(void* const* d_in, const int* in_sizes, int n_in,
                              void* d_out, int out_size, void* d_ws, size_t ws_size,
                              hipStream_t stream) {
    const int*   indices    = (const int*)  d_in[0];
    const float* mask       = (const float*)d_in[1];
    const int*   labels     = (const int*)  d_in[2];
    const float* label_mask = (const float*)d_in[3];
    const int*   negs       = (const int*)  d_in[4];
    const float* embed      = (const float*)d_in[5];
    const float* Wk         = (const float*)d_in[6];
    float* out = (float*)d_out;

    // workspace layout (~21 MB)
    unsigned short* WT  = (unsigned short*)d_ws;                    // NSUB*DDIM bf16
    unsigned short* qbf = WT + (size_t)NSUB * DDIM;                 // BDIM*DDIM bf16
    int*   srt_v      = (int*)(qbf + (size_t)BDIM * DDIM);          // NSUB
    int*   rank       = srt_v + NSUB;                               // NSUB
    float* norms2     = (float*)(rank + NSUB);                      // NSUB
    float* pos_scores = norms2 + NSUB;                              // NPOS
    float* Zrow       = pos_scores + NPOS;                          // BDIM
    float* accum      = Zrow + BDIM;                                // 2
    int*   ticket     = (int*)(accum + 2);                          // 1
    int*   cntg       = ticket + 1;                                 // NBUCK
    int*   offs_end   = cntg + NBUCK;                               // NBUCK

    sortinit_kernel<<<1 + NSUB / 1024, 1024, 0, stream>>>(labels, negs, offs_end, cntg,
                                                          srt_v, rank, norms2, Zrow,
                                                          accum, ticket);
    main1_kernel<<<M1_BLOCKS, 256, 0, stream>>>(Wk, srt_v, offs_end, cntg, WT, norms2,
                                                indices, mask, embed, qbf);
    main2_kernel<<<(BDIM / 64) * (NNEG / 64) + NPOS / 64, 256, 0, stream>>>(
        qbf, WT, rank, norms2, pos_scores, Zrow);
    finalize_kernel<<<NPOS / 256, 256, 0, stream>>>(pos_scores, label_mask, Zrow,
                                                    accum, ticket, out);
}

// Round 12
// 127.125 us; speedup vs baseline: 1.2084x; 1.0211x over previous
//
#include <hip/hip_runtime.h>
#include <hip/hip_bf16.h>

#define BDIM 1024
#define LDIM 128
#define KDIM 16
#define DDIM 512
#define NLAB 131072
#define NNEG 2048
#define NPOS (BDIM * KDIM)      /* 16384 */
#define NSUB (NPOS + NNEG)      /* 18432 */
#define EPSV 0.1f
#define CV 2.1f
#define NBUCK 512               /* labels per bucket = 256 -> shift 8 */
#define DCHUNKS 16              /* 512 / 32 */
#define GT_BLOCKS (NBUCK * DCHUNKS)   /* 8192 W-tile blocks */
#define QY_BLOCKS (BDIM * 4)          /* 4096 query blocks (b x col-quarter) */
#define M1_BLOCKS (QY_BLOCKS + GT_BLOCKS)  /* 12288 */

typedef __attribute__((ext_vector_type(8))) short s8v;
typedef __attribute__((ext_vector_type(4))) float f4v;
typedef __attribute__((ext_vector_type(4))) float fv4;
typedef __attribute__((ext_vector_type(2))) float fv2;
typedef __attribute__((ext_vector_type(4))) unsigned short us4;

static __device__ __forceinline__ unsigned short f2bf(float x) {
    union { float f; unsigned u; } v; v.f = x;
    unsigned r = v.u + 0x7FFF + ((v.u >> 16) & 1);   // RNE
    return (unsigned short)(r >> 16);
}
static __device__ __forceinline__ float bf2f(unsigned short h) {
    return __uint_as_float((unsigned)h << 16);
}

// ---------------- sortinit: block 0 = bucket sort; blocks 1..18 = zero fill ----------------
__global__ __launch_bounds__(1024) void sortinit_kernel(const int* __restrict__ labels,
                                                        const int* __restrict__ negs,
                                                        int* __restrict__ offs_end,
                                                        int* __restrict__ cntg,
                                                        int* __restrict__ srt_v,
                                                        int* __restrict__ rank,
                                                        float* __restrict__ norms2,
                                                        float* __restrict__ Zrow,
                                                        float* __restrict__ ssq,
                                                        float* __restrict__ accum,
                                                        int* __restrict__ ticket) {
    int t = threadIdx.x;
    if (blockIdx.x != 0) {
        int j = (blockIdx.x - 1) * 1024 + t;   // covers NSUB with 18 blocks
        if (j < NSUB) norms2[j] = 0.f;
        if (j < BDIM) { Zrow[j] = 0.f; ssq[j] = 0.f; }
        if (j < 2) accum[j] = 0.f;
        if (j == 0) *ticket = 0;
        return;
    }
    __shared__ int sc[NBUCK];
    if (t < NBUCK) sc[t] = 0;
    __syncthreads();
    int vs[NSUB / 1024];
    #pragma unroll
    for (int k = 0; k < NSUB / 1024; ++k) {
        int j = k * 1024 + t;
        int v = (j < NPOS) ? max(labels[j], 0) : negs[j - NPOS];
        vs[k] = v;
        atomicAdd(&sc[v >> 8], 1);
    }
    __syncthreads();
    int c = (t < NBUCK) ? sc[t] : 0;
    for (int off = 1; off < NBUCK; off <<= 1) {
        int v2 = (t < NBUCK && t >= off) ? sc[t - off] : 0;
        __syncthreads();
        if (t < NBUCK) sc[t] += v2;
        __syncthreads();
    }
    if (t < NBUCK) { cntg[t] = c; sc[t] -= c; }   // sc = exclusive bucket base
    __syncthreads();
    #pragma unroll
    for (int k = 0; k < NSUB / 1024; ++k) {
        int j = k * 1024 + t;
        int v = vs[k];
        int r = atomicAdd(&sc[v >> 8], 1);
        srt_v[r] = v;
        rank[j] = r;
    }
    __syncthreads();
    if (t < NBUCK) offs_end[t] = sc[t];           // bucket end
}

// ---------------- main1: INTERLEAVED [query col-quarters] and [W bucket-stream] ----------------
__global__ __launch_bounds__(256) void main1_kernel(const float* __restrict__ Wk,
                                                    const int* __restrict__ srt_v,
                                                    const int* __restrict__ offs_end,
                                                    const int* __restrict__ cnt,
                                                    unsigned short* __restrict__ WT,
                                                    float* __restrict__ norms2,
                                                    const int* __restrict__ indices,
                                                    const float* __restrict__ mask,
                                                    const float* __restrict__ embed,
                                                    float* __restrict__ qacc,
                                                    float* __restrict__ ssq) {
    __shared__ __align__(16) unsigned short tile[256][33];   // 16.9 KB -> 8 blocks/CU
    int t = threadIdx.x;
    int w = t >> 6, l = t & 63;
    int bx = blockIdx.x;

    if (bx % 3 == 0) {
        // ---- query quarter: block = (b, col-quarter). Wave w owns rows [w*32,w*32+32);
        //      lane owns 2 cols. Denominator cancels in normalize -> only raw sum + ssq.
        char* base = (char*)&tile[0][0];
        int*   sidx    = (int*)base;                  // 128 ints
        float* smask   = (float*)(base + 512);        // 128 floats
        float* partial = (float*)(base + 1024);       // [4][128] floats
        int q = bx / 3;
        int b = q >> 2;
        int qt = q & 3;
        int c0 = qt * 128;
        if (t < LDIM) {
            sidx[t]  = indices[b * LDIM + t];
            smask[t] = mask[b * LDIM + t];
        }
        __syncthreads();
        fv2 acc = {0.f, 0.f};
        #pragma unroll 8
        for (int i = 0; i < 32; ++i) {
            int row = w * 32 + i;
            int idx = sidx[row];
            float m = smask[row];
            fv2 v = *(const fv2*)&embed[(size_t)idx * DDIM + c0 + l * 2];
            acc += v * m;
        }
        partial[w * 128 + l * 2]     = acc[0];
        partial[w * 128 + l * 2 + 1] = acc[1];
        __syncthreads();
        if (t < 128) {
            float x = partial[t] + partial[128 + t] + partial[256 + t] + partial[384 + t];
            qacc[(size_t)b * DDIM + c0 + t] = x;
            float ss = x * x;
            #pragma unroll
            for (int off = 32; off > 0; off >>= 1) ss += __shfl_xor(ss, off, 64);
            if (l == 0) atomicAdd(&ssq[b], ss);
        }
    } else {
        // ---- W bucket-stream: block = (bucket g, 32-d chunk) ----
        int bt = bx - bx / 3 - 1;   // 0..8191
        int g  = bt >> 4;           // 0..511
        int dc = bt & 15;           // 0..15
        int d0 = dc * 32;
        #pragma unroll
        for (int i = 0; i < 8; ++i) {
            int dl = w * 8 + i;
            fv4 v = __builtin_nontemporal_load(
                (const fv4*)&Wk[(size_t)(d0 + dl) * NLAB + g * 256 + l * 4]);
            tile[l * 4 + 0][dl] = f2bf(v[0]);
            tile[l * 4 + 1][dl] = f2bf(v[1]);
            tile[l * 4 + 2][dl] = f2bf(v[2]);
            tile[l * 4 + 3][dl] = f2bf(v[3]);
        }
        __syncthreads();
        int rend = offs_end[g];
        int rbeg = rend - cnt[g];
        int ld = l & 31, lh = l >> 5;
        for (int r = rbeg + w * 2 + lh; r < rend; r += 8) {
            int v = srt_v[r];
            int col = v - g * 256;
            unsigned short h = tile[col][ld];
            WT[(size_t)r * DDIM + d0 + ld] = h;
            float f = bf2f(h);
            float ss = f * f;
            ss += __shfl_xor(ss, 1, 64);  ss += __shfl_xor(ss, 2, 64);
            ss += __shfl_xor(ss, 4, 64);  ss += __shfl_xor(ss, 8, 64);
            ss += __shfl_xor(ss, 16, 64);
            if (ld == 0) atomicAdd(&norms2[r], ss);
        }
    }
}

// ---------------- normalize: qbf[b][c] = bf16(qacc[b][c]/||qacc[b]||) ----------------
__global__ __launch_bounds__(256) void normalize_kernel(const float* __restrict__ qacc,
                                                        const float* __restrict__ ssq,
                                                        unsigned short* __restrict__ qbf) {
    int t = threadIdx.x;
    int b = blockIdx.x * 2 + (t >> 7);
    int c = (t & 127) * 4;
    float inv = 1.f / fmaxf(sqrtf(ssq[b]), 1e-6f);
    fv4 v = *(const fv4*)&qacc[(size_t)b * DDIM + c];
    v *= inv;
    us4 o = { f2bf(v[0]), f2bf(v[1]), f2bf(v[2]), f2bf(v[3]) };
    *(us4*)&qbf[(size_t)b * DDIM + c] = o;
}

// ---------------- main2: fused [neg MFMA GEMM] and [pos dots] ----------------
static __device__ __forceinline__ float score_of(float acc, float nn) {
    float dot = acc / nn;
    dot = fminf(fmaxf(dot, -0.999f), 0.999f);
    return dot * dot / fmaxf(CV - 2.f * dot, EPSV);
}

__global__ __launch_bounds__(256) void main2_kernel(const unsigned short* __restrict__ qbf,
                                                    const unsigned short* __restrict__ WT,
                                                    const int* __restrict__ rank,
                                                    const float* __restrict__ norms2,
                                                    float* __restrict__ pos_scores,
                                                    float* __restrict__ Zrow) {
    int t = threadIdx.x;
    int w = t >> 6, l = t & 63;
    if (blockIdx.x < (BDIM / 64) * (NNEG / 64)) {
        // ---- negatives: 64x64 tile via MFMA ----
        __shared__ float rowsum[64];
        int bx = blockIdx.x;
        int mt = bx & 15, nt = bx >> 4;
        int wm = w >> 1, wn = w & 1;
        int lr = l & 15, lg = l >> 4;
        int m0 = mt * 64 + wm * 32;
        int n0 = nt * 64 + wn * 32;
        if (t < 64) rowsum[t] = 0.f;
        __syncthreads();

        int rB0 = rank[NPOS + n0 + lr];
        int rB1 = rank[NPOS + n0 + 16 + lr];
        const unsigned short* a0p = qbf + (size_t)(m0 + lr) * DDIM + lg * 8;
        const unsigned short* a1p = qbf + (size_t)(m0 + 16 + lr) * DDIM + lg * 8;
        const unsigned short* b0p = WT + (size_t)rB0 * DDIM + lg * 8;
        const unsigned short* b1p = WT + (size_t)rB1 * DDIM + lg * 8;

        f4v acc00 = {0.f, 0.f, 0.f, 0.f}, acc01 = acc00, acc10 = acc00, acc11 = acc00;
        #pragma unroll
        for (int k0 = 0; k0 < DDIM; k0 += 32) {
            s8v a0 = *(const s8v*)(a0p + k0);
            s8v a1 = *(const s8v*)(a1p + k0);
            s8v b0 = *(const s8v*)(b0p + k0);
            s8v b1 = *(const s8v*)(b1p + k0);
            acc00 = __builtin_amdgcn_mfma_f32_16x16x32_bf16(a0, b0, acc00, 0, 0, 0);
            acc01 = __builtin_amdgcn_mfma_f32_16x16x32_bf16(a0, b1, acc01, 0, 0, 0);
            acc10 = __builtin_amdgcn_mfma_f32_16x16x32_bf16(a1, b0, acc10, 0, 0, 0);
            acc11 = __builtin_amdgcn_mfma_f32_16x16x32_bf16(a1, b1, acc11, 0, 0, 0);
        }

        float nn0 = fmaxf(sqrtf(norms2[rB0]), 1e-4f);
        float nn1 = fmaxf(sqrtf(norms2[rB1]), 1e-4f);
        float s[8];
        #pragma unroll
        for (int i = 0; i < 4; ++i) {
            s[i]     = score_of(acc00[i], nn0) + score_of(acc01[i], nn1);
            s[4 + i] = score_of(acc10[i], nn0) + score_of(acc11[i], nn1);
        }
        #pragma unroll
        for (int i = 0; i < 8; ++i) {
            s[i] += __shfl_xor(s[i], 1, 64);
            s[i] += __shfl_xor(s[i], 2, 64);
            s[i] += __shfl_xor(s[i], 4, 64);
            s[i] += __shfl_xor(s[i], 8, 64);
        }
        if (lr == 0) {
            #pragma unroll
            for (int i = 0; i < 4; ++i) {
                atomicAdd(&rowsum[wm * 32 + lg * 4 + i], s[i]);
                atomicAdd(&rowsum[wm * 32 + 16 + lg * 4 + i], s[4 + i]);
            }
        }
        __syncthreads();
        if (t < 64) atomicAdd(&Zrow[mt * 64 + t], rowsum[t]);
    } else {
        // ---- positives: wave handles one b (16 j) ----
        int px = blockIdx.x - (BDIM / 64) * (NNEG / 64);
        int b = px * 4 + w;
        int j = b * KDIM + (l & 15);
        int r = rank[j];
        int g = l >> 4;
        const unsigned short* wrow = WT + (size_t)r * DDIM + g * 128;
        const unsigned short* qrow = qbf + (size_t)b * DDIM + g * 128;
        float acc = 0.f;
        #pragma unroll
        for (int kk = 0; kk < 128; kk += 8) {
            ushort4 w0 = *(const ushort4*)&wrow[kk];
            ushort4 w1 = *(const ushort4*)&wrow[kk + 4];
            ushort4 q0 = *(const ushort4*)&qrow[kk];
            ushort4 q1 = *(const ushort4*)&qrow[kk + 4];
            acc += bf2f(w0.x) * bf2f(q0.x) + bf2f(w0.y) * bf2f(q0.y)
                 + bf2f(w0.z) * bf2f(q0.z) + bf2f(w0.w) * bf2f(q0.w)
                 + bf2f(w1.x) * bf2f(q1.x) + bf2f(w1.y) * bf2f(q1.y)
                 + bf2f(w1.z) * bf2f(q1.z) + bf2f(w1.w) * bf2f(q1.w);
        }
        acc += __shfl_xor(acc, 16, 64);
        acc += __shfl_xor(acc, 32, 64);
        if (l < 16) {
            float nrm = fmaxf(sqrtf(norms2[r]), 1e-4f);
            float dot = fminf(fmaxf(acc / nrm, -0.999f), 0.999f);
            float sc = dot * dot / fmaxf(CV - 2.f * dot, EPSV);
            pos_scores[j] = sc;
            float s = sc;
            s += __shfl_xor(s, 1, 64); s += __shfl_xor(s, 2, 64);
            s += __shfl_xor(s, 4, 64); s += __shfl_xor(s, 8, 64);
            if (l == 0) atomicAdd(&Zrow[b], s);
        }
    }
}

// ---------------- finalize (+writeout via ticket) ----------------
__global__ __launch_bounds__(256) void finalize_kernel(const float* __restrict__ pos_scores,
                                                       const float* __restrict__ label_mask,
                                                       const float* __restrict__ Zrow,
                                                       float* __restrict__ accum,
                                                       int* __restrict__ ticket,
                                                       float* __restrict__ out) {
    int j = blockIdx.x * 256 + threadIdx.x;
    int b = j >> 4;
    float lm = label_mask[j];
    float logZ = logf(Zrow[b] + (float)(KDIM + NNEG) * 1e-8f);
    float v = lm * (logf(pos_scores[j] + 1e-8f) - logZ);
    #pragma unroll
    for (int off = 32; off > 0; off >>= 1) {
        v  += __shfl_down(v, off, 64);
        lm += __shfl_down(lm, off, 64);
    }
    __shared__ float rv[4], rl[4];
    int wid = threadIdx.x >> 6, lane = threadIdx.x & 63;
    if (lane == 0) { rv[wid] = v; rl[wid] = lm; }
    __syncthreads();
    if (threadIdx.x == 0) {
        atomicAdd(&accum[0], rv[0] + rv[1] + rv[2] + rv[3]);
        atomicAdd(&accum[1], rl[0] + rl[1] + rl[2] + rl[3]);
        __threadfence();
        int old = atomicAdd(ticket, 1);
        if (old == (int)gridDim.x - 1) {
            float a = atomicAdd(&accum[0], 0.f);
            float m = atomicAdd(&accum[1], 0.f);
            out[0] = -a / (m + 1e-6f);
        }
    }
}

extern "C" void kernel_launch(void* const* d_in, const int* in_sizes, int n_in,
                              void* d_out, int out_size, void* d_ws, size_t ws_size,
                              hipStream_t stream) {
    const int*   indices    = (const int*)  d_in[0];
    const float* mask       = (const float*)d_in[1];
    const int*   labels     = (const int*)  d_in[2];
    const float* label_mask = (const float*)d_in[3];
    const int*   negs       = (const int*)  d_in[4];
    const float* embed      = (const float*)d_in[5];
    const float* Wk         = (const float*)d_in[6];
    float* out = (float*)d_out;

    // workspace layout (~23 MB)
    unsigned short* WT  = (unsigned short*)d_ws;                    // NSUB*DDIM bf16
    unsigned short* qbf = WT + (size_t)NSUB * DDIM;                 // BDIM*DDIM bf16
    float* qacc       = (float*)(qbf + (size_t)BDIM * DDIM);        // BDIM*DDIM f32
    float* ssq        = qacc + (size_t)BDIM * DDIM;                 // BDIM
    int*   srt_v      = (int*)(ssq + BDIM);                         // NSUB
    int*   rank       = srt_v + NSUB;                               // NSUB
    float* norms2     = (float*)(rank + NSUB);                      // NSUB
    float* pos_scores = norms2 + NSUB;                              // NPOS
    float* Zrow       = pos_scores + NPOS;                          // BDIM
    float* accum      = Zrow + BDIM;                                // 2
    int*   ticket     = (int*)(accum + 2);                          // 1
    int*   cntg       = ticket + 1;                                 // NBUCK
    int*   offs_end   = cntg + NBUCK;                               // NBUCK

    sortinit_kernel<<<1 + NSUB / 1024, 1024, 0, stream>>>(labels, negs, offs_end, cntg,
                                                          srt_v, rank, norms2, Zrow, ssq,
                                                          accum, ticket);
    main1_kernel<<<M1_BLOCKS, 256, 0, stream>>>(Wk, srt_v, offs_end, cntg, WT, norms2,
                                                indices, mask, embed, qacc, ssq);
    normalize_kernel<<<BDIM / 2, 256, 0, stream>>>(qacc, ssq, qbf);
    main2_kernel<<<(BDIM / 64) * (NNEG / 64) + NPOS / 64, 256, 0, stream>>>(
        qbf, WT, rank, norms2, pos_scores, Zrow);
    finalize_kernel<<<NPOS / 256, 256, 0, stream>>>(pos_scores, label_mask, Zrow,
                                                    accum, ticket, out);
}